// Round 3
// baseline (1571.564 us; speedup 1.0000x reference)
//
#include <hip/hip_runtime.h>
#include <hip/hip_bf16.h>

#define T_TOKENS 8192
#define D_DIM 1024
#define H_DIM 4096
#define E_NUM 8
#define CAP 8192
#define BM 128
#define BN 128
#define BK 64

typedef short bf16x8 __attribute__((ext_vector_type(8)));
typedef float f32x4 __attribute__((ext_vector_type(4)));
typedef unsigned short u16x8 __attribute__((ext_vector_type(8)));

__device__ inline unsigned short f2bf(float f) {
    union { float f; unsigned int u; } v; v.f = f;
    unsigned int u = v.u;
    return (unsigned short)((u + 0x7fffu + ((u >> 16) & 1u)) >> 16);  // RNE
}

__device__ inline float gelu_tanh(float v) {
    float c = 0.7978845608028654f * (v + 0.044715f * v * v * v);
    float t = 1.0f - 2.0f / (__expf(2.0f * c) + 1.0f);   // tanh(c)
    return 0.5f * v * (1.0f + t);
}

// async global->LDS, 16B/lane; lds base wave-uniform (HW adds lane*16)
__device__ inline void gld_lds16(const unsigned short* g, unsigned short* lds) {
    __builtin_amdgcn_global_load_lds(
        (const __attribute__((address_space(1))) void*)g,
        (__attribute__((address_space(3))) void*)lds, 16, 0, 0);
}

// ---------------- gate: logits (fp64 acc), top-2, softmax, routing lists ---
__global__ __launch_bounds__(256) void gate_kernel(const float* __restrict__ x,
                                                   const float* __restrict__ gw,
                                                   int* __restrict__ cnt,
                                                   int* __restrict__ tok,
                                                   float* __restrict__ cf) {
    int lane = threadIdx.x & 63;
    int t = blockIdx.x * 4 + (threadIdx.x >> 6);
    const float* xr = x + (size_t)t * D_DIM;
    double acc[E_NUM];
#pragma unroll
    for (int e = 0; e < E_NUM; ++e) acc[e] = 0.0;
    for (int d = lane; d < D_DIM; d += 64) {
        double xv = (double)xr[d];
        const float* g = gw + (size_t)d * E_NUM;
#pragma unroll
        for (int e = 0; e < E_NUM; ++e) acc[e] += xv * (double)g[e];
    }
#pragma unroll
    for (int e = 0; e < E_NUM; ++e) {
        double v = acc[e];
#pragma unroll
        for (int off = 32; off >= 1; off >>= 1) v += __shfl_xor(v, off);
        acc[e] = v;
    }
    if (lane == 0) {
        int s0 = 0;
#pragma unroll
        for (int e = 1; e < E_NUM; ++e) if (acc[e] > acc[s0]) s0 = e;
        int s1 = -1;
#pragma unroll
        for (int e = 0; e < E_NUM; ++e) if (e != s0 && (s1 < 0 || acc[e] > acc[s1])) s1 = e;
        float l0 = (float)acc[s0], l1 = (float)acc[s1];
        float p1 = __expf(l1 - l0);
        float inv = 1.0f / (1.0f + p1);
        int q0 = atomicAdd(&cnt[s0], 1);
        tok[s0 * CAP + q0] = t;  cf[s0 * CAP + q0] = inv;
        int q1 = atomicAdd(&cnt[s1], 1);
        tok[s1 * CAP + q1] = t;  cf[s1 * CAP + q1] = p1 * inv;
    }
}

// ---------------- prepass: x fp32 -> bf16 ----------------------------------
__global__ __launch_bounds__(256) void cvt_x_kernel(const float* __restrict__ x,
                                                    unsigned short* __restrict__ xb) {
    size_t i = ((size_t)blockIdx.x * 256 + threadIdx.x) * 8;
    float4 v0 = *(const float4*)(x + i);
    float4 v1 = *(const float4*)(x + i + 4);
    u16x8 u;
    u[0] = f2bf(v0.x); u[1] = f2bf(v0.y); u[2] = f2bf(v0.z); u[3] = f2bf(v0.w);
    u[4] = f2bf(v1.x); u[5] = f2bf(v1.y); u[6] = f2bf(v1.z); u[7] = f2bf(v1.w);
    *(u16x8*)(xb + i) = u;
}

// ---------------- prepass: w [E][K][N] fp32 -> wt [E][N][K] bf16 -----------
__global__ __launch_bounds__(256) void trw_kernel(const float* __restrict__ w,
                                                  unsigned short* __restrict__ wt,
                                                  int K, int N) {
    __shared__ float t[64][132];
    int e = blockIdx.z;
    int k0 = blockIdx.y * 64;
    int n0 = blockIdx.x * 128;
    const float* we = w + (size_t)e * K * N;
    unsigned short* wte = wt + (size_t)e * K * N;
    int tid = threadIdx.x;
    int rk = tid >> 5;
    int rn = (tid & 31) * 4;
#pragma unroll
    for (int p = 0; p < 8; ++p) {
        int k = rk + p * 8;
        float4 v = *(const float4*)(we + (size_t)(k0 + k) * N + n0 + rn);
        t[k][rn] = v.x; t[k][rn + 1] = v.y; t[k][rn + 2] = v.z; t[k][rn + 3] = v.w;
    }
    __syncthreads();
    int n = tid >> 1;
    int kc = (tid & 1) * 32;
    unsigned short* dst = wte + (size_t)(n0 + n) * K + k0 + kc;
#pragma unroll
    for (int c8 = 0; c8 < 4; ++c8) {
        u16x8 u;
#pragma unroll
        for (int c = 0; c < 8; ++c) u[c] = f2bf(t[kc + c8 * 8 + c][n]);
        *(u16x8*)(dst + c8 * 8) = u;
    }
}

// ================= GEMMs: 2-phase prefetch (T3-min), double-buffered LDS ===

__global__ __launch_bounds__(256, 2) void gemm1_fast(const unsigned short* __restrict__ xb,
                                                     const unsigned short* __restrict__ w1t,
                                                     const float* __restrict__ b1,
                                                     const int* __restrict__ cnt,
                                                     const int* __restrict__ tok,
                                                     unsigned short* __restrict__ Hbuf) {
    int e = blockIdx.z;
    int ne = cnt[e];
    int bm0 = blockIdx.x * BM;
    if (bm0 >= ne) return;
    int n0 = blockIdx.y * BN;
    int offs = 0;
#pragma unroll
    for (int i = 0; i < E_NUM; ++i) offs += (i < e) ? cnt[i] : 0;

    __shared__ __align__(16) unsigned short As[2][BM][BK];
    __shared__ __align__(16) unsigned short Bs[2][BN][BK];
    __shared__ int s_tok[BM];

    int tid = threadIdx.x, lane = tid & 63, wv = tid >> 6;
    if (tid < BM) s_tok[tid] = tok[e * CAP + min(bm0 + tid, ne - 1)];

    int wr = (wv >> 1) * 64, wc = (wv & 1) * 64;
    int lm = lane & 15, lk = lane >> 4;
    int lrow8 = lane >> 3;
    int lk8 = (lane & 7) * 8;

    const unsigned short* w1e = w1t + (size_t)e * H_DIM * D_DIM;  // [n][k]

    f32x4 acc[4][4];
#pragma unroll
    for (int i = 0; i < 4; ++i)
#pragma unroll
        for (int j = 0; j < 4; ++j) { f32x4 z = {0.f, 0.f, 0.f, 0.f}; acc[i][j] = z; }

    auto STAGE = [&](int buf, int kb) {
        int k0 = kb * BK;
#pragma unroll
        for (int i = 0; i < 4; ++i) {
            int r0 = (i * 4 + wv) * 8;
            gld_lds16(xb + (size_t)s_tok[r0 + lrow8] * D_DIM + k0 + lk8, &As[buf][r0][0]);
            gld_lds16(w1e + (size_t)(n0 + r0 + lrow8) * D_DIM + k0 + lk8, &Bs[buf][r0][0]);
        }
    };

    __syncthreads();             // s_tok visible
    STAGE(0, 0);
    __syncthreads();             // drain prologue stage

    const int NT = D_DIM / BK;
    int cur = 0;
    for (int kb = 0; kb < NT; ++kb) {
        if (kb + 1 < NT) STAGE(cur ^ 1, kb + 1);   // prefetch next tile
#pragma unroll
        for (int ks = 0; ks < 2; ++ks) {
            bf16x8 a[4], b[4];
            int kbase = ks * 32 + lk * 8;
#pragma unroll
            for (int f = 0; f < 4; ++f) a[f] = *(const bf16x8*)&As[cur][wr + f * 16 + lm][kbase];
#pragma unroll
            for (int f = 0; f < 4; ++f) b[f] = *(const bf16x8*)&Bs[cur][wc + f * 16 + lm][kbase];
#pragma unroll
            for (int i = 0; i < 4; ++i)
#pragma unroll
                for (int j = 0; j < 4; ++j)
                    acc[i][j] = __builtin_amdgcn_mfma_f32_16x16x32_bf16(a[i], b[j], acc[i][j], 0, 0, 0);
        }
        __syncthreads();         // drains vmcnt(0): prefetch had full compute phase in flight
        cur ^= 1;
    }

    const float* b1e = b1 + (size_t)e * H_DIM;
#pragma unroll
    for (int i = 0; i < 4; ++i) {
#pragma unroll
        for (int r = 0; r < 4; ++r) {
            int row = wr + i * 16 + lk * 4 + r;
            int gr = bm0 + row;
            if (gr >= ne) continue;
            size_t rb = (size_t)(offs + gr) * H_DIM;
#pragma unroll
            for (int j = 0; j < 4; ++j) {
                int gn = n0 + wc + j * 16 + lm;
                float v = acc[i][j][r] + b1e[gn];
                Hbuf[rb + gn] = f2bf(gelu_tanh(v));
            }
        }
    }
}

__global__ __launch_bounds__(256, 2) void gemm2_fast(const unsigned short* __restrict__ Hbuf,
                                                     const unsigned short* __restrict__ w2t,
                                                     const float* __restrict__ b2,
                                                     const int* __restrict__ cnt,
                                                     const int* __restrict__ tok,
                                                     const float* __restrict__ cf,
                                                     float* __restrict__ out) {
    int e = blockIdx.z;
    int ne = cnt[e];
    int bm0 = blockIdx.x * BM;
    if (bm0 >= ne) return;
    int n0 = blockIdx.y * BN;
    int offs = 0;
#pragma unroll
    for (int i = 0; i < E_NUM; ++i) offs += (i < e) ? cnt[i] : 0;

    __shared__ __align__(16) unsigned short As[2][BM][BK];
    __shared__ __align__(16) unsigned short Bs[2][BN][BK];
    __shared__ int s_tok[BM];
    __shared__ float s_cf[BM];

    int tid = threadIdx.x, lane = tid & 63, wv = tid >> 6;
    if (tid < BM) {
        int gi = min(bm0 + tid, ne - 1);
        s_tok[tid] = tok[e * CAP + gi];
        s_cf[tid] = cf[e * CAP + gi];
    }

    int wr = (wv >> 1) * 64, wc = (wv & 1) * 64;
    int lm = lane & 15, lk = lane >> 4;
    int lrow8 = lane >> 3;
    int lk8 = (lane & 7) * 8;

    const unsigned short* w2e = w2t + (size_t)e * H_DIM * D_DIM;  // [n][k]

    f32x4 acc[4][4];
#pragma unroll
    for (int i = 0; i < 4; ++i)
#pragma unroll
        for (int j = 0; j < 4; ++j) { f32x4 z = {0.f, 0.f, 0.f, 0.f}; acc[i][j] = z; }

    // A rows are expert-compacted (contiguous): clamp handled here
    int arow = min(bm0 + 0, ne - 1);  // base; per-group rows clamped below
    (void)arow;

    auto STAGE = [&](int buf, int kb) {
        int k0 = kb * BK;
#pragma unroll
        for (int i = 0; i < 4; ++i) {
            int r0 = (i * 4 + wv) * 8;
            size_t src = (size_t)(offs + min(bm0 + r0 + lrow8, ne - 1)) * H_DIM + k0 + lk8;
            gld_lds16(Hbuf + src, &As[buf][r0][0]);
            gld_lds16(w2e + (size_t)(n0 + r0 + lrow8) * H_DIM + k0 + lk8, &Bs[buf][r0][0]);
        }
    };

    __syncthreads();
    STAGE(0, 0);
    __syncthreads();

    const int NT = H_DIM / BK;
    int cur = 0;
    for (int kb = 0; kb < NT; ++kb) {
        if (kb + 1 < NT) STAGE(cur ^ 1, kb + 1);
#pragma unroll
        for (int ks = 0; ks < 2; ++ks) {
            bf16x8 a[4], b[4];
            int kbase = ks * 32 + lk * 8;
#pragma unroll
            for (int f = 0; f < 4; ++f) a[f] = *(const bf16x8*)&As[cur][wr + f * 16 + lm][kbase];
#pragma unroll
            for (int f = 0; f < 4; ++f) b[f] = *(const bf16x8*)&Bs[cur][wc + f * 16 + lm][kbase];
#pragma unroll
            for (int i = 0; i < 4; ++i)
#pragma unroll
                for (int j = 0; j < 4; ++j)
                    acc[i][j] = __builtin_amdgcn_mfma_f32_16x16x32_bf16(a[i], b[j], acc[i][j], 0, 0, 0);
        }
        __syncthreads();
        cur ^= 1;
    }

    const float* b2e = b2 + (size_t)e * D_DIM;
#pragma unroll
    for (int i = 0; i < 4; ++i) {
#pragma unroll
        for (int r = 0; r < 4; ++r) {
            int row = wr + i * 16 + lk * 4 + r;
            int gr = bm0 + row;
            if (gr >= ne) continue;
            int tk = s_tok[row];
            float w = s_cf[row];
#pragma unroll
            for (int j = 0; j < 4; ++j) {
                int gn = n0 + wc + j * 16 + lm;
                float y = acc[i][j][r] + b2e[gn];
                atomicAdd(&out[(size_t)tk * D_DIM + gn], w * y);
            }
        }
    }
}

extern "C" void kernel_launch(void* const* d_in, const int* in_sizes, int n_in,
                              void* d_out, int out_size, void* d_ws, size_t ws_size,
                              hipStream_t stream) {
    const float* x  = (const float*)d_in[0];
    const float* gw = (const float*)d_in[1];
    const float* w1 = (const float*)d_in[2];
    const float* b1 = (const float*)d_in[3];
    const float* w2 = (const float*)d_in[4];
    const float* b2 = (const float*)d_in[5];
    float* out = (float*)d_out;

    char* ws = (char*)d_ws;
    const size_t SZ_ROUTE = 256 + (size_t)2 * E_NUM * CAP * 4;
    const size_t SZ_XB    = (size_t)T_TOKENS * D_DIM * 2;
    const size_t SZ_W     = (size_t)E_NUM * D_DIM * H_DIM * 2;
    const size_t SZ_H     = (size_t)2 * T_TOKENS * H_DIM * 2;

    int*   cnt = (int*)ws;
    int*   tok = (int*)(ws + 256);
    float* cff = (float*)(ws + 256 + E_NUM * CAP * 4);

    size_t need_fast = SZ_ROUTE + SZ_XB + 2 * SZ_W + SZ_H;
    if (ws_size < need_fast) return;  // loud failure: out stays poisoned

    hipMemsetAsync(cnt, 0, E_NUM * sizeof(int), stream);
    hipMemsetAsync(out, 0, (size_t)out_size * sizeof(float), stream);
    gate_kernel<<<T_TOKENS / 4, 256, 0, stream>>>(x, gw, cnt, tok, cff);

    unsigned short* xb   = (unsigned short*)(ws + SZ_ROUTE);
    unsigned short* w1t  = (unsigned short*)(ws + SZ_ROUTE + SZ_XB);
    unsigned short* w2t  = (unsigned short*)(ws + SZ_ROUTE + SZ_XB + SZ_W);
    unsigned short* Hbuf = (unsigned short*)(ws + SZ_ROUTE + SZ_XB + 2 * SZ_W);

    cvt_x_kernel<<<T_TOKENS * D_DIM / 8 / 256, 256, 0, stream>>>(x, xb);
    dim3 gt1(H_DIM / 128, D_DIM / 64, E_NUM);
    trw_kernel<<<gt1, 256, 0, stream>>>(w1, w1t, D_DIM, H_DIM);
    dim3 gt2(D_DIM / 128, H_DIM / 64, E_NUM);
    trw_kernel<<<gt2, 256, 0, stream>>>(w2, w2t, H_DIM, D_DIM);

    dim3 g1(CAP / BM, H_DIM / BN, E_NUM);
    gemm1_fast<<<g1, 256, 0, stream>>>(xb, w1t, b1, cnt, tok, Hbuf);
    dim3 g2(CAP / BM, D_DIM / BN, E_NUM);
    gemm2_fast<<<g2, 256, 0, stream>>>(Hbuf, w2t, b2, cnt, tok, cff, out);
}

// Round 4
// 929.275 us; speedup vs baseline: 1.6912x; 1.6912x over previous
//
#include <hip/hip_runtime.h>
#include <hip/hip_bf16.h>

#define T_TOKENS 8192
#define D_DIM 1024
#define H_DIM 4096
#define E_NUM 8
#define CAP 8192
#define BM 128
#define BN 128
#define BK 64
#define NBM (CAP / BM)          // 64 bm blocks (worst case)

typedef short bf16x8 __attribute__((ext_vector_type(8)));
typedef float f32x4 __attribute__((ext_vector_type(4)));
typedef unsigned short u16x8 __attribute__((ext_vector_type(8)));

__device__ inline unsigned short f2bf(float f) {
    union { float f; unsigned int u; } v; v.f = f;
    unsigned int u = v.u;
    return (unsigned short)((u + 0x7fffu + ((u >> 16) & 1u)) >> 16);  // RNE
}

__device__ inline float gelu_tanh(float v) {
    float c = 0.7978845608028654f * (v + 0.044715f * v * v * v);
    float t = 1.0f - 2.0f / (__expf(2.0f * c) + 1.0f);   // tanh(c)
    return 0.5f * v * (1.0f + t);
}

// async global->LDS, 16B/lane; lds base wave-uniform (HW adds lane*16)
__device__ inline void gld_lds16(const unsigned short* g, unsigned short* lds) {
    __builtin_amdgcn_global_load_lds(
        (const __attribute__((address_space(1))) void*)g,
        (__attribute__((address_space(3))) void*)lds, 16, 0, 0);
}

// ---------------- gate ------------------------------------------------------
__global__ __launch_bounds__(256) void gate_kernel(const float* __restrict__ x,
                                                   const float* __restrict__ gw,
                                                   int* __restrict__ cnt,
                                                   int* __restrict__ tok,
                                                   float* __restrict__ cf) {
    int lane = threadIdx.x & 63;
    int t = blockIdx.x * 4 + (threadIdx.x >> 6);
    const float* xr = x + (size_t)t * D_DIM;
    double acc[E_NUM];
#pragma unroll
    for (int e = 0; e < E_NUM; ++e) acc[e] = 0.0;
    for (int d = lane; d < D_DIM; d += 64) {
        double xv = (double)xr[d];
        const float* g = gw + (size_t)d * E_NUM;
#pragma unroll
        for (int e = 0; e < E_NUM; ++e) acc[e] += xv * (double)g[e];
    }
#pragma unroll
    for (int e = 0; e < E_NUM; ++e) {
        double v = acc[e];
#pragma unroll
        for (int off = 32; off >= 1; off >>= 1) v += __shfl_xor(v, off);
        acc[e] = v;
    }
    if (lane == 0) {
        int s0 = 0;
#pragma unroll
        for (int e = 1; e < E_NUM; ++e) if (acc[e] > acc[s0]) s0 = e;
        int s1 = -1;
#pragma unroll
        for (int e = 0; e < E_NUM; ++e) if (e != s0 && (s1 < 0 || acc[e] > acc[s1])) s1 = e;
        float l0 = (float)acc[s0], l1 = (float)acc[s1];
        float p1 = __expf(l1 - l0);
        float inv = 1.0f / (1.0f + p1);
        int q0 = atomicAdd(&cnt[s0], 1);
        tok[s0 * CAP + q0] = t;  cf[s0 * CAP + q0] = inv;
        int q1 = atomicAdd(&cnt[s1], 1);
        tok[s1 * CAP + q1] = t;  cf[s1 * CAP + q1] = p1 * inv;
    }
}

// ---------------- prepasses -------------------------------------------------
__global__ __launch_bounds__(256) void cvt_x_kernel(const float* __restrict__ x,
                                                    unsigned short* __restrict__ xb) {
    size_t i = ((size_t)blockIdx.x * 256 + threadIdx.x) * 8;
    float4 v0 = *(const float4*)(x + i);
    float4 v1 = *(const float4*)(x + i + 4);
    u16x8 u;
    u[0] = f2bf(v0.x); u[1] = f2bf(v0.y); u[2] = f2bf(v0.z); u[3] = f2bf(v0.w);
    u[4] = f2bf(v1.x); u[5] = f2bf(v1.y); u[6] = f2bf(v1.z); u[7] = f2bf(v1.w);
    *(u16x8*)(xb + i) = u;
}

__global__ __launch_bounds__(256) void trw_kernel(const float* __restrict__ w,
                                                  unsigned short* __restrict__ wt,
                                                  int K, int N) {
    __shared__ float t[64][132];
    int e = blockIdx.z;
    int k0 = blockIdx.y * 64;
    int n0 = blockIdx.x * 128;
    const float* we = w + (size_t)e * K * N;
    unsigned short* wte = wt + (size_t)e * K * N;
    int tid = threadIdx.x;
    int rk = tid >> 5;
    int rn = (tid & 31) * 4;
#pragma unroll
    for (int p = 0; p < 8; ++p) {
        int k = rk + p * 8;
        float4 v = *(const float4*)(we + (size_t)(k0 + k) * N + n0 + rn);
        t[k][rn] = v.x; t[k][rn + 1] = v.y; t[k][rn + 2] = v.z; t[k][rn + 3] = v.w;
    }
    __syncthreads();
    int n = tid >> 1;
    int kc = (tid & 1) * 32;
    unsigned short* dst = wte + (size_t)(n0 + n) * K + k0 + kc;
#pragma unroll
    for (int c8 = 0; c8 < 4; ++c8) {
        u16x8 u;
#pragma unroll
        for (int c = 0; c < 8; ++c) u[c] = f2bf(t[kc + c8 * 8 + c][n]);
        *(u16x8*)(dst + c8 * 8) = u;
    }
}

// ================= GEMMs: 2-phase, STATIC double-buffer, XCD swizzle =======

#define DECODE_SWZ(NBN_)                                                      \
    int total = E_NUM * NBM * (NBN_);                                         \
    int cpx = total >> 3;                                                     \
    int bid = blockIdx.x;                                                     \
    int swz = (bid & 7) * cpx + (bid >> 3);                                   \
    int e = swz / (NBM * (NBN_));                                             \
    int rem = swz - e * (NBM * (NBN_));                                       \
    int n_idx = rem / NBM;                                                    \
    int bm_idx = rem - n_idx * NBM;

__global__ __launch_bounds__(256, 2) void gemm1_fast(const unsigned short* __restrict__ xb,
                                                     const unsigned short* __restrict__ w1t,
                                                     const float* __restrict__ b1,
                                                     const int* __restrict__ cnt,
                                                     const int* __restrict__ tok,
                                                     unsigned short* __restrict__ Hbuf) {
    DECODE_SWZ(H_DIM / BN)
    int ne = cnt[e];
    int bm0 = bm_idx * BM;
    if (bm0 >= ne) return;
    int n0 = n_idx * BN;
    int offs = 0;
#pragma unroll
    for (int i = 0; i < E_NUM; ++i) offs += (i < e) ? cnt[i] : 0;

    __shared__ __align__(16) unsigned short As0[BM][BK], Bs0[BN][BK];
    __shared__ __align__(16) unsigned short As1[BM][BK], Bs1[BN][BK];
    __shared__ int s_tok[BM];

    int tid = threadIdx.x, lane = tid & 63, wv = tid >> 6;
    if (tid < BM) s_tok[tid] = tok[e * CAP + min(bm0 + tid, ne - 1)];

    int wr = (wv >> 1) * 64, wc = (wv & 1) * 64;
    int lm = lane & 15, lk = lane >> 4;
    int lrow8 = lane >> 3;
    int lk8 = (lane & 7) * 8;

    const unsigned short* w1e = w1t + (size_t)e * H_DIM * D_DIM;  // [n][k]

    __syncthreads();   // s_tok visible

    // hoisted per-lane global base pointers (row base + lane k-chunk)
    const unsigned short* gA[4];
    const unsigned short* gB[4];
#pragma unroll
    for (int i = 0; i < 4; ++i) {
        int r0 = (i * 4 + wv) * 8;
        gA[i] = xb + (size_t)s_tok[r0 + lrow8] * D_DIM + lk8;
        gB[i] = w1e + (size_t)(n0 + r0 + lrow8) * D_DIM + lk8;
    }

    f32x4 acc[4][4];
#pragma unroll
    for (int i = 0; i < 4; ++i)
#pragma unroll
        for (int j = 0; j < 4; ++j) { f32x4 z = {0.f, 0.f, 0.f, 0.f}; acc[i][j] = z; }

    auto STAGE = [&](unsigned short (&A)[BM][BK], unsigned short (&B)[BN][BK], int kb) {
        int k0 = kb * BK;
#pragma unroll
        for (int i = 0; i < 4; ++i) {
            int r0 = (i * 4 + wv) * 8;
            gld_lds16(gA[i] + k0, &A[r0][0]);
            gld_lds16(gB[i] + k0, &B[r0][0]);
        }
    };
    auto COMPUTE = [&](unsigned short (&A)[BM][BK], unsigned short (&B)[BN][BK]) {
#pragma unroll
        for (int ks = 0; ks < 2; ++ks) {
            bf16x8 a[4], b[4];
            int kbase = ks * 32 + lk * 8;
#pragma unroll
            for (int f = 0; f < 4; ++f) a[f] = *(const bf16x8*)&A[wr + f * 16 + lm][kbase];
#pragma unroll
            for (int f = 0; f < 4; ++f) b[f] = *(const bf16x8*)&B[wc + f * 16 + lm][kbase];
#pragma unroll
            for (int i = 0; i < 4; ++i)
#pragma unroll
                for (int j = 0; j < 4; ++j)
                    acc[i][j] = __builtin_amdgcn_mfma_f32_16x16x32_bf16(a[i], b[j], acc[i][j], 0, 0, 0);
        }
    };

    const int NT = D_DIM / BK;   // 16, even
    STAGE(As0, Bs0, 0);
    __syncthreads();             // drain prologue
    for (int kb = 0; kb < NT; kb += 2) {
        STAGE(As1, Bs1, kb + 1);      // in flight during compute of buf0
        COMPUTE(As0, Bs0);
        __syncthreads();              // vmcnt(0) drain: had full MFMA phase to land
        if (kb + 2 < NT) STAGE(As0, Bs0, kb + 2);
        COMPUTE(As1, Bs1);
        if (kb + 2 < NT) __syncthreads();
    }

    const float* b1e = b1 + (size_t)e * H_DIM;
#pragma unroll
    for (int i = 0; i < 4; ++i) {
#pragma unroll
        for (int r = 0; r < 4; ++r) {
            int row = wr + i * 16 + lk * 4 + r;
            int gr = bm0 + row;
            if (gr >= ne) continue;
            size_t rb = (size_t)(offs + gr) * H_DIM;
#pragma unroll
            for (int j = 0; j < 4; ++j) {
                int gn = n0 + wc + j * 16 + lm;
                float v = acc[i][j][r] + b1e[gn];
                Hbuf[rb + gn] = f2bf(gelu_tanh(v));
            }
        }
    }
}

__global__ __launch_bounds__(256, 2) void gemm2_fast(const unsigned short* __restrict__ Hbuf,
                                                     const unsigned short* __restrict__ w2t,
                                                     const float* __restrict__ b2,
                                                     const int* __restrict__ cnt,
                                                     const int* __restrict__ tok,
                                                     const float* __restrict__ cf,
                                                     float* __restrict__ out) {
    DECODE_SWZ(D_DIM / BN)
    int ne = cnt[e];
    int bm0 = bm_idx * BM;
    if (bm0 >= ne) return;
    int n0 = n_idx * BN;
    int offs = 0;
#pragma unroll
    for (int i = 0; i < E_NUM; ++i) offs += (i < e) ? cnt[i] : 0;

    __shared__ __align__(16) unsigned short As0[BM][BK], Bs0[BN][BK];
    __shared__ __align__(16) unsigned short As1[BM][BK], Bs1[BN][BK];
    __shared__ int s_tok[BM];
    __shared__ float s_cf[BM];

    int tid = threadIdx.x, lane = tid & 63, wv = tid >> 6;
    if (tid < BM) {
        int gi = min(bm0 + tid, ne - 1);
        s_tok[tid] = tok[e * CAP + gi];
        s_cf[tid] = cf[e * CAP + gi];
    }

    int wr = (wv >> 1) * 64, wc = (wv & 1) * 64;
    int lm = lane & 15, lk = lane >> 4;
    int lrow8 = lane >> 3;
    int lk8 = (lane & 7) * 8;

    const unsigned short* w2e = w2t + (size_t)e * H_DIM * D_DIM;  // [n][k]

    const unsigned short* gA[4];
    const unsigned short* gB[4];
#pragma unroll
    for (int i = 0; i < 4; ++i) {
        int r0 = (i * 4 + wv) * 8;
        gA[i] = Hbuf + (size_t)(offs + min(bm0 + r0 + lrow8, ne - 1)) * H_DIM + lk8;
        gB[i] = w2e + (size_t)(n0 + r0 + lrow8) * H_DIM + lk8;
    }

    f32x4 acc[4][4];
#pragma unroll
    for (int i = 0; i < 4; ++i)
#pragma unroll
        for (int j = 0; j < 4; ++j) { f32x4 z = {0.f, 0.f, 0.f, 0.f}; acc[i][j] = z; }

    auto STAGE = [&](unsigned short (&A)[BM][BK], unsigned short (&B)[BN][BK], int kb) {
        int k0 = kb * BK;
#pragma unroll
        for (int i = 0; i < 4; ++i) {
            int r0 = (i * 4 + wv) * 8;
            gld_lds16(gA[i] + k0, &A[r0][0]);
            gld_lds16(gB[i] + k0, &B[r0][0]);
        }
    };
    auto COMPUTE = [&](unsigned short (&A)[BM][BK], unsigned short (&B)[BN][BK]) {
#pragma unroll
        for (int ks = 0; ks < 2; ++ks) {
            bf16x8 a[4], b[4];
            int kbase = ks * 32 + lk * 8;
#pragma unroll
            for (int f = 0; f < 4; ++f) a[f] = *(const bf16x8*)&A[wr + f * 16 + lm][kbase];
#pragma unroll
            for (int f = 0; f < 4; ++f) b[f] = *(const bf16x8*)&B[wc + f * 16 + lm][kbase];
#pragma unroll
            for (int i = 0; i < 4; ++i)
#pragma unroll
                for (int j = 0; j < 4; ++j)
                    acc[i][j] = __builtin_amdgcn_mfma_f32_16x16x32_bf16(a[i], b[j], acc[i][j], 0, 0, 0);
        }
    };

    __syncthreads();   // s_tok/s_cf visible (gA uses only offs/ne which are per-thread)

    const int NT = H_DIM / BK;   // 64, even
    STAGE(As0, Bs0, 0);
    __syncthreads();
    for (int kb = 0; kb < NT; kb += 2) {
        STAGE(As1, Bs1, kb + 1);
        COMPUTE(As0, Bs0);
        __syncthreads();
        if (kb + 2 < NT) STAGE(As0, Bs0, kb + 2);
        COMPUTE(As1, Bs1);
        if (kb + 2 < NT) __syncthreads();
    }

    const float* b2e = b2 + (size_t)e * D_DIM;
#pragma unroll
    for (int i = 0; i < 4; ++i) {
#pragma unroll
        for (int r = 0; r < 4; ++r) {
            int row = wr + i * 16 + lk * 4 + r;
            int gr = bm0 + row;
            if (gr >= ne) continue;
            int tk = s_tok[row];
            float w = s_cf[row];
#pragma unroll
            for (int j = 0; j < 4; ++j) {
                int gn = n0 + wc + j * 16 + lm;
                float y = acc[i][j][r] + b2e[gn];
                atomicAdd(&out[(size_t)tk * D_DIM + gn], w * y);
            }
        }
    }
}

extern "C" void kernel_launch(void* const* d_in, const int* in_sizes, int n_in,
                              void* d_out, int out_size, void* d_ws, size_t ws_size,
                              hipStream_t stream) {
    const float* x  = (const float*)d_in[0];
    const float* gw = (const float*)d_in[1];
    const float* w1 = (const float*)d_in[2];
    const float* b1 = (const float*)d_in[3];
    const float* w2 = (const float*)d_in[4];
    const float* b2 = (const float*)d_in[5];
    float* out = (float*)d_out;

    char* ws = (char*)d_ws;
    const size_t SZ_ROUTE = 256 + (size_t)2 * E_NUM * CAP * 4;
    const size_t SZ_XB    = (size_t)T_TOKENS * D_DIM * 2;
    const size_t SZ_W     = (size_t)E_NUM * D_DIM * H_DIM * 2;
    const size_t SZ_H     = (size_t)2 * T_TOKENS * H_DIM * 2;

    int*   cnt = (int*)ws;
    int*   tok = (int*)(ws + 256);
    float* cff = (float*)(ws + 256 + E_NUM * CAP * 4);

    size_t need_fast = SZ_ROUTE + SZ_XB + 2 * SZ_W + SZ_H;
    if (ws_size < need_fast) return;  // loud failure: out stays poisoned

    hipMemsetAsync(cnt, 0, E_NUM * sizeof(int), stream);
    hipMemsetAsync(out, 0, (size_t)out_size * sizeof(float), stream);
    gate_kernel<<<T_TOKENS / 4, 256, 0, stream>>>(x, gw, cnt, tok, cff);

    unsigned short* xb   = (unsigned short*)(ws + SZ_ROUTE);
    unsigned short* w1t  = (unsigned short*)(ws + SZ_ROUTE + SZ_XB);
    unsigned short* w2t  = (unsigned short*)(ws + SZ_ROUTE + SZ_XB + SZ_W);
    unsigned short* Hbuf = (unsigned short*)(ws + SZ_ROUTE + SZ_XB + 2 * SZ_W);

    cvt_x_kernel<<<T_TOKENS * D_DIM / 8 / 256, 256, 0, stream>>>(x, xb);
    dim3 gt1(H_DIM / 128, D_DIM / 64, E_NUM);
    trw_kernel<<<gt1, 256, 0, stream>>>(w1, w1t, D_DIM, H_DIM);
    dim3 gt2(D_DIM / 128, H_DIM / 64, E_NUM);
    trw_kernel<<<gt2, 256, 0, stream>>>(w2, w2t, H_DIM, D_DIM);

    gemm1_fast<<<E_NUM * NBM * (H_DIM / BN), 256, 0, stream>>>(xb, w1t, b1, cnt, tok, Hbuf);
    gemm2_fast<<<E_NUM * NBM * (D_DIM / BN), 256, 0, stream>>>(Hbuf, w2t, b2, cnt, tok, cff, out);
}

// Round 5
// 915.239 us; speedup vs baseline: 1.7171x; 1.0153x over previous
//
#include <hip/hip_runtime.h>
#include <hip/hip_bf16.h>

#define T_TOKENS 8192
#define D_DIM 1024
#define H_DIM 4096
#define E_NUM 8
#define CAP 8192
#define BM 128
#define BN 128
#define BK 64
#define NBM (CAP / BM)          // 64 bm blocks (worst case)

typedef short bf16x8 __attribute__((ext_vector_type(8)));
typedef float f32x4 __attribute__((ext_vector_type(4)));
typedef unsigned short u16x8 __attribute__((ext_vector_type(8)));

__device__ inline unsigned short f2bf(float f) {
    union { float f; unsigned int u; } v; v.f = f;
    unsigned int u = v.u;
    return (unsigned short)((u + 0x7fffu + ((u >> 16) & 1u)) >> 16);  // RNE
}

__device__ inline float gelu_tanh(float v) {
    float c = 0.7978845608028654f * (v + 0.044715f * v * v * v);
    float t = 1.0f - 2.0f / (__expf(2.0f * c) + 1.0f);   // tanh(c)
    return 0.5f * v * (1.0f + t);
}

// async global->LDS, 16B/lane; lds base wave-uniform (HW adds lane*16)
__device__ inline void gld_lds16(const unsigned short* g, unsigned short* lds) {
    __builtin_amdgcn_global_load_lds(
        (const __attribute__((address_space(1))) void*)g,
        (__attribute__((address_space(3))) void*)lds, 16, 0, 0);
}

// counted waits + raw barrier (rule 18: pin with sched_barrier(0))
#define WAITV8 do { asm volatile("s_waitcnt vmcnt(8)" ::: "memory"); \
                    __builtin_amdgcn_sched_barrier(0); } while (0)
#define WAITV0 do { asm volatile("s_waitcnt vmcnt(0)" ::: "memory"); \
                    __builtin_amdgcn_sched_barrier(0); } while (0)
#define SBAR   do { __builtin_amdgcn_sched_barrier(0); \
                    __builtin_amdgcn_s_barrier(); \
                    __builtin_amdgcn_sched_barrier(0); } while (0)

// ---------------- gate (+ fused x fp32->bf16 conversion) -------------------
__global__ __launch_bounds__(256) void gate_kernel(const float* __restrict__ x,
                                                   const float* __restrict__ gw,
                                                   int* __restrict__ cnt,
                                                   int* __restrict__ tok,
                                                   float* __restrict__ cf,
                                                   unsigned short* __restrict__ xb) {
    int lane = threadIdx.x & 63;
    int t = blockIdx.x * 4 + (threadIdx.x >> 6);
    const float* xr = x + (size_t)t * D_DIM;
    unsigned short* xbr = xb + (size_t)t * D_DIM;
    double acc[E_NUM];
#pragma unroll
    for (int e = 0; e < E_NUM; ++e) acc[e] = 0.0;
#pragma unroll
    for (int it = 0; it < 4; ++it) {
        int d = it * 256 + lane * 4;
        float4 v = *(const float4*)(xr + d);
        ushort4 u;
        u.x = f2bf(v.x); u.y = f2bf(v.y); u.z = f2bf(v.z); u.w = f2bf(v.w);
        *(ushort4*)(xbr + d) = u;
        const float vv[4] = {v.x, v.y, v.z, v.w};
#pragma unroll
        for (int j = 0; j < 4; ++j) {
            const float* g = gw + (size_t)(d + j) * E_NUM;
#pragma unroll
            for (int e = 0; e < E_NUM; ++e) acc[e] += (double)vv[j] * (double)g[e];
        }
    }
#pragma unroll
    for (int e = 0; e < E_NUM; ++e) {
        double v = acc[e];
#pragma unroll
        for (int off = 32; off >= 1; off >>= 1) v += __shfl_xor(v, off);
        acc[e] = v;
    }
    if (lane == 0) {
        int s0 = 0;
#pragma unroll
        for (int e = 1; e < E_NUM; ++e) if (acc[e] > acc[s0]) s0 = e;
        int s1 = -1;
#pragma unroll
        for (int e = 0; e < E_NUM; ++e) if (e != s0 && (s1 < 0 || acc[e] > acc[s1])) s1 = e;
        float l0 = (float)acc[s0], l1 = (float)acc[s1];
        float p1 = __expf(l1 - l0);
        float inv = 1.0f / (1.0f + p1);
        int q0 = atomicAdd(&cnt[s0], 1);
        tok[s0 * CAP + q0] = t;  cf[s0 * CAP + q0] = inv;
        int q1 = atomicAdd(&cnt[s1], 1);
        tok[s1 * CAP + q1] = t;  cf[s1 * CAP + q1] = p1 * inv;
    }
}

// ---------------- prepass: w [E][K][N] fp32 -> wt [E][N][K] bf16 -----------
__global__ __launch_bounds__(256) void trw_kernel(const float* __restrict__ w,
                                                  unsigned short* __restrict__ wt,
                                                  int K, int N) {
    __shared__ float t[64][132];
    int e = blockIdx.z;
    int k0 = blockIdx.y * 64;
    int n0 = blockIdx.x * 128;
    const float* we = w + (size_t)e * K * N;
    unsigned short* wte = wt + (size_t)e * K * N;
    int tid = threadIdx.x;
    int rk = tid >> 5;
    int rn = (tid & 31) * 4;
#pragma unroll
    for (int p = 0; p < 8; ++p) {
        int k = rk + p * 8;
        float4 v = *(const float4*)(we + (size_t)(k0 + k) * N + n0 + rn);
        t[k][rn] = v.x; t[k][rn + 1] = v.y; t[k][rn + 2] = v.z; t[k][rn + 3] = v.w;
    }
    __syncthreads();
    int n = tid >> 1;
    int kc = (tid & 1) * 32;
    unsigned short* dst = wte + (size_t)(n0 + n) * K + k0 + kc;
#pragma unroll
    for (int c8 = 0; c8 < 4; ++c8) {
        u16x8 u;
#pragma unroll
        for (int c = 0; c < 8; ++c) u[c] = f2bf(t[kc + c8 * 8 + c][n]);
        *(u16x8*)(dst + c8 * 8) = u;
    }
}

// ================= GEMMs: depth-2 prefetch, counted vmcnt, raw barriers ====
// LDS k-chunk swizzle: LDS[row][chunk] holds global chunk (chunk ^ (row&7)).
// Staged via pre-swizzled per-lane SOURCE (#21); reads XOR the same pattern.

#define DECODE_SWZ(NBN_)                                                      \
    int total = E_NUM * NBM * (NBN_);                                         \
    int cpx = total >> 3;                                                     \
    int bid = blockIdx.x;                                                     \
    int swz = (bid & 7) * cpx + (bid >> 3);                                   \
    int e = swz / (NBM * (NBN_));                                             \
    int rem = swz - e * (NBM * (NBN_));                                       \
    int n_idx = rem / NBM;                                                    \
    int bm_idx = rem - n_idx * NBM;

__global__ __launch_bounds__(256, 2) void gemm1_fast(const unsigned short* __restrict__ xb,
                                                     const unsigned short* __restrict__ w1t,
                                                     const float* __restrict__ b1,
                                                     const int* __restrict__ cnt,
                                                     const int* __restrict__ tok,
                                                     unsigned short* __restrict__ Hbuf) {
    DECODE_SWZ(H_DIM / BN)
    int ne = cnt[e];
    int bm0 = bm_idx * BM;
    if (bm0 >= ne) return;
    int n0 = n_idx * BN;
    int offs = 0;
#pragma unroll
    for (int i = 0; i < E_NUM; ++i) offs += (i < e) ? cnt[i] : 0;

    __shared__ __align__(16) unsigned short As0[BM][BK], Bs0[BN][BK];
    __shared__ __align__(16) unsigned short As1[BM][BK], Bs1[BN][BK];
    __shared__ int s_tok[BM];

    int tid = threadIdx.x, lane = tid & 63, wv = tid >> 6;
    if (tid < BM) s_tok[tid] = tok[e * CAP + min(bm0 + tid, ne - 1)];

    int wr = (wv >> 1) * 64, wc = (wv & 1) * 64;
    int lm = lane & 15, lk = lane >> 4;
    int lrow8 = lane >> 3;
    // pre-swizzled source k-offset: chunk_src = (lane&7) ^ (row&7), row&7 = lane>>3
    int lk8s = (((lane & 7) ^ (lrow8 & 7)) << 3);

    const unsigned short* w1e = w1t + (size_t)e * H_DIM * D_DIM;  // [n][k]

    __syncthreads();   // s_tok visible; drains all prior vmem -> vmcnt clean

    const unsigned short* gA[4];
    const unsigned short* gB[4];
#pragma unroll
    for (int i = 0; i < 4; ++i) {
        int r0 = (i * 4 + wv) * 8;
        gA[i] = xb + (size_t)s_tok[r0 + lrow8] * D_DIM + lk8s;
        gB[i] = w1e + (size_t)(n0 + r0 + lrow8) * D_DIM + lk8s;
    }

    f32x4 acc[4][4];
#pragma unroll
    for (int i = 0; i < 4; ++i)
#pragma unroll
        for (int j = 0; j < 4; ++j) { f32x4 z = {0.f, 0.f, 0.f, 0.f}; acc[i][j] = z; }

    auto STAGE = [&](unsigned short (&A)[BM][BK], unsigned short (&B)[BN][BK], int kb) {
        int k0 = kb * BK;
#pragma unroll
        for (int i = 0; i < 4; ++i) {
            int r0 = (i * 4 + wv) * 8;
            gld_lds16(gA[i] + k0, &A[r0][0]);
            gld_lds16(gB[i] + k0, &B[r0][0]);
        }
    };
    auto COMPUTE = [&](unsigned short (&A)[BM][BK], unsigned short (&B)[BN][BK]) {
#pragma unroll
        for (int ks = 0; ks < 2; ++ks) {
            bf16x8 a[4], b[4];
            int kidx = (((ks * 4 + lk) ^ (lm & 7)) << 3);   // swizzled chunk
#pragma unroll
            for (int f = 0; f < 4; ++f) a[f] = *(const bf16x8*)&A[wr + f * 16 + lm][kidx];
#pragma unroll
            for (int f = 0; f < 4; ++f) b[f] = *(const bf16x8*)&B[wc + f * 16 + lm][kidx];
#pragma unroll
            for (int i = 0; i < 4; ++i)
#pragma unroll
                for (int j = 0; j < 4; ++j)
                    acc[i][j] = __builtin_amdgcn_mfma_f32_16x16x32_bf16(a[i], b[j], acc[i][j], 0, 0, 0);
        }
    };

    const int NT = D_DIM / BK;   // 16
    STAGE(As0, Bs0, 0);          // 8 loads
    STAGE(As1, Bs1, 1);          // 8 loads
    for (int t = 0; t < NT - 1; ++t) {
        WAITV8;                  // tile t's 8 oldest loads complete
        SBAR;                    // publish buf(t&1); prior reads of other buf done
        if (t & 1) COMPUTE(As1, Bs1); else COMPUTE(As0, Bs0);
        SBAR;                    // all waves done reading buf(t&1)
        if (t + 2 < NT) {
            if (t & 1) STAGE(As1, Bs1, t + 2); else STAGE(As0, Bs0, t + 2);
        }
    }
    WAITV0;
    SBAR;
    COMPUTE(As1, Bs1);           // NT-1 odd (NT=16)

    const float* b1e = b1 + (size_t)e * H_DIM;
#pragma unroll
    for (int i = 0; i < 4; ++i) {
#pragma unroll
        for (int r = 0; r < 4; ++r) {
            int row = wr + i * 16 + lk * 4 + r;
            int gr = bm0 + row;
            if (gr >= ne) continue;
            size_t rb = (size_t)(offs + gr) * H_DIM;
#pragma unroll
            for (int j = 0; j < 4; ++j) {
                int gn = n0 + wc + j * 16 + lm;
                float v = acc[i][j][r] + b1e[gn];
                Hbuf[rb + gn] = f2bf(gelu_tanh(v));
            }
        }
    }
}

__global__ __launch_bounds__(256, 2) void gemm2_fast(const unsigned short* __restrict__ Hbuf,
                                                     const unsigned short* __restrict__ w2t,
                                                     const float* __restrict__ b2,
                                                     const int* __restrict__ cnt,
                                                     const int* __restrict__ tok,
                                                     const float* __restrict__ cf,
                                                     float* __restrict__ out) {
    DECODE_SWZ(D_DIM / BN)
    int ne = cnt[e];
    int bm0 = bm_idx * BM;
    if (bm0 >= ne) return;
    int n0 = n_idx * BN;
    int offs = 0;
#pragma unroll
    for (int i = 0; i < E_NUM; ++i) offs += (i < e) ? cnt[i] : 0;

    __shared__ __align__(16) unsigned short As0[BM][BK], Bs0[BN][BK];
    __shared__ __align__(16) unsigned short As1[BM][BK], Bs1[BN][BK];
    __shared__ int s_tok[BM];
    __shared__ float s_cf[BM];

    int tid = threadIdx.x, lane = tid & 63, wv = tid >> 6;
    if (tid < BM) {
        int gi = min(bm0 + tid, ne - 1);
        s_tok[tid] = tok[e * CAP + gi];
        s_cf[tid] = cf[e * CAP + gi];
    }

    int wr = (wv >> 1) * 64, wc = (wv & 1) * 64;
    int lm = lane & 15, lk = lane >> 4;
    int lrow8 = lane >> 3;
    int lk8s = (((lane & 7) ^ (lrow8 & 7)) << 3);

    const unsigned short* w2e = w2t + (size_t)e * H_DIM * D_DIM;  // [n][k]

    const unsigned short* gA[4];
    const unsigned short* gB[4];
#pragma unroll
    for (int i = 0; i < 4; ++i) {
        int r0 = (i * 4 + wv) * 8;
        gA[i] = Hbuf + (size_t)(offs + min(bm0 + r0 + lrow8, ne - 1)) * H_DIM + lk8s;
        gB[i] = w2e + (size_t)(n0 + r0 + lrow8) * H_DIM + lk8s;
    }

    f32x4 acc[4][4];
#pragma unroll
    for (int i = 0; i < 4; ++i)
#pragma unroll
        for (int j = 0; j < 4; ++j) { f32x4 z = {0.f, 0.f, 0.f, 0.f}; acc[i][j] = z; }

    auto STAGE = [&](unsigned short (&A)[BM][BK], unsigned short (&B)[BN][BK], int kb) {
        int k0 = kb * BK;
#pragma unroll
        for (int i = 0; i < 4; ++i) {
            int r0 = (i * 4 + wv) * 8;
            gld_lds16(gA[i] + k0, &A[r0][0]);
            gld_lds16(gB[i] + k0, &B[r0][0]);
        }
    };
    auto COMPUTE = [&](unsigned short (&A)[BM][BK], unsigned short (&B)[BN][BK]) {
#pragma unroll
        for (int ks = 0; ks < 2; ++ks) {
            bf16x8 a[4], b[4];
            int kidx = (((ks * 4 + lk) ^ (lm & 7)) << 3);
#pragma unroll
            for (int f = 0; f < 4; ++f) a[f] = *(const bf16x8*)&A[wr + f * 16 + lm][kidx];
#pragma unroll
            for (int f = 0; f < 4; ++f) b[f] = *(const bf16x8*)&B[wc + f * 16 + lm][kidx];
#pragma unroll
            for (int i = 0; i < 4; ++i)
#pragma unroll
                for (int j = 0; j < 4; ++j)
                    acc[i][j] = __builtin_amdgcn_mfma_f32_16x16x32_bf16(a[i], b[j], acc[i][j], 0, 0, 0);
        }
    };

    __syncthreads();   // s_tok/s_cf visible; vmcnt drained clean

    const int NT = H_DIM / BK;   // 64
    STAGE(As0, Bs0, 0);
    STAGE(As1, Bs1, 1);
    for (int t = 0; t < NT - 1; ++t) {
        WAITV8;
        SBAR;
        if (t & 1) COMPUTE(As1, Bs1); else COMPUTE(As0, Bs0);
        SBAR;
        if (t + 2 < NT) {
            if (t & 1) STAGE(As1, Bs1, t + 2); else STAGE(As0, Bs0, t + 2);
        }
    }
    WAITV0;
    SBAR;
    COMPUTE(As1, Bs1);           // NT-1 odd (NT=64)

    const float* b2e = b2 + (size_t)e * D_DIM;
#pragma unroll
    for (int i = 0; i < 4; ++i) {
#pragma unroll
        for (int r = 0; r < 4; ++r) {
            int row = wr + i * 16 + lk * 4 + r;
            int gr = bm0 + row;
            if (gr >= ne) continue;
            int tk = s_tok[row];
            float w = s_cf[row];
#pragma unroll
            for (int j = 0; j < 4; ++j) {
                int gn = n0 + wc + j * 16 + lm;
                float y = acc[i][j][r] + b2e[gn];
                atomicAdd(&out[(size_t)tk * D_DIM + gn], w * y);
            }
        }
    }
}

extern "C" void kernel_launch(void* const* d_in, const int* in_sizes, int n_in,
                              void* d_out, int out_size, void* d_ws, size_t ws_size,
                              hipStream_t stream) {
    const float* x  = (const float*)d_in[0];
    const float* gw = (const float*)d_in[1];
    const float* w1 = (const float*)d_in[2];
    const float* b1 = (const float*)d_in[3];
    const float* w2 = (const float*)d_in[4];
    const float* b2 = (const float*)d_in[5];
    float* out = (float*)d_out;

    char* ws = (char*)d_ws;
    const size_t SZ_ROUTE = 256 + (size_t)2 * E_NUM * CAP * 4;
    const size_t SZ_XB    = (size_t)T_TOKENS * D_DIM * 2;
    const size_t SZ_W     = (size_t)E_NUM * D_DIM * H_DIM * 2;
    const size_t SZ_H     = (size_t)2 * T_TOKENS * H_DIM * 2;

    int*   cnt = (int*)ws;
    int*   tok = (int*)(ws + 256);
    float* cff = (float*)(ws + 256 + E_NUM * CAP * 4);

    size_t need_fast = SZ_ROUTE + SZ_XB + 2 * SZ_W + SZ_H;
    if (ws_size < need_fast) return;  // loud failure: out stays poisoned

    unsigned short* xb   = (unsigned short*)(ws + SZ_ROUTE);
    unsigned short* w1t  = (unsigned short*)(ws + SZ_ROUTE + SZ_XB);
    unsigned short* w2t  = (unsigned short*)(ws + SZ_ROUTE + SZ_XB + SZ_W);
    unsigned short* Hbuf = (unsigned short*)(ws + SZ_ROUTE + SZ_XB + 2 * SZ_W);

    hipMemsetAsync(cnt, 0, E_NUM * sizeof(int), stream);
    hipMemsetAsync(out, 0, (size_t)out_size * sizeof(float), stream);

    gate_kernel<<<T_TOKENS / 4, 256, 0, stream>>>(x, gw, cnt, tok, cff, xb);

    dim3 gt1(H_DIM / 128, D_DIM / 64, E_NUM);
    trw_kernel<<<gt1, 256, 0, stream>>>(w1, w1t, D_DIM, H_DIM);
    dim3 gt2(D_DIM / 128, H_DIM / 64, E_NUM);
    trw_kernel<<<gt2, 256, 0, stream>>>(w2, w2t, H_DIM, D_DIM);

    gemm1_fast<<<E_NUM * NBM * (H_DIM / BN), 256, 0, stream>>>(xb, w1t, b1, cnt, tok, Hbuf);
    gemm2_fast<<<E_NUM * NBM * (D_DIM / BN), 256, 0, stream>>>(Hbuf, w2t, b2, cnt, tok, cff, out);
}

// Round 6
// 885.876 us; speedup vs baseline: 1.7740x; 1.0331x over previous
//
#include <hip/hip_runtime.h>
#include <hip/hip_bf16.h>

#define T_TOKENS 8192
#define D_DIM 1024
#define H_DIM 4096
#define E_NUM 8
#define CAP 8192
#define BM 128
#define BN 128
#define BK 32            // K-step per LDS buffer (4 buffers, depth-4 pipeline)
#define NBM (CAP / BM)   // 64 bm blocks (worst case)

typedef short bf16x8 __attribute__((ext_vector_type(8)));
typedef float f32x4 __attribute__((ext_vector_type(4)));
typedef unsigned short u16x8 __attribute__((ext_vector_type(8)));

__device__ inline unsigned short f2bf(float f) {
    union { float f; unsigned int u; } v; v.f = f;
    unsigned int u = v.u;
    return (unsigned short)((u + 0x7fffu + ((u >> 16) & 1u)) >> 16);  // RNE
}

__device__ inline float gelu_tanh(float v) {
    float c = 0.7978845608028654f * (v + 0.044715f * v * v * v);
    float t = 1.0f - 2.0f / (__expf(2.0f * c) + 1.0f);   // tanh(c)
    return 0.5f * v * (1.0f + t);
}

// async global->LDS, 16B/lane; lds base wave-uniform (HW adds lane*16)
__device__ inline void gld_lds16(const unsigned short* g, unsigned short* lds) {
    __builtin_amdgcn_global_load_lds(
        (const __attribute__((address_space(1))) void*)g,
        (__attribute__((address_space(3))) void*)lds, 16, 0, 0);
}

// counted waits + raw barrier (rule 18: pin with sched_barrier(0))
#define WAITV(N) do { asm volatile("s_waitcnt vmcnt(" #N ")" ::: "memory"); \
                      __builtin_amdgcn_sched_barrier(0); } while (0)
#define SBAR     do { __builtin_amdgcn_sched_barrier(0); \
                      __builtin_amdgcn_s_barrier(); \
                      __builtin_amdgcn_sched_barrier(0); } while (0)

// ---------------- gate (+ fused x fp32->bf16 conversion) -------------------
__global__ __launch_bounds__(256) void gate_kernel(const float* __restrict__ x,
                                                   const float* __restrict__ gw,
                                                   int* __restrict__ cnt,
                                                   int* __restrict__ tok,
                                                   float* __restrict__ cf,
                                                   unsigned short* __restrict__ xb) {
    int lane = threadIdx.x & 63;
    int t = blockIdx.x * 4 + (threadIdx.x >> 6);
    const float* xr = x + (size_t)t * D_DIM;
    unsigned short* xbr = xb + (size_t)t * D_DIM;
    double acc[E_NUM];
#pragma unroll
    for (int e = 0; e < E_NUM; ++e) acc[e] = 0.0;
#pragma unroll
    for (int it = 0; it < 4; ++it) {
        int d = it * 256 + lane * 4;
        float4 v = *(const float4*)(xr + d);
        ushort4 u;
        u.x = f2bf(v.x); u.y = f2bf(v.y); u.z = f2bf(v.z); u.w = f2bf(v.w);
        *(ushort4*)(xbr + d) = u;
        const float vv[4] = {v.x, v.y, v.z, v.w};
#pragma unroll
        for (int j = 0; j < 4; ++j) {
            const float* g = gw + (size_t)(d + j) * E_NUM;
#pragma unroll
            for (int e = 0; e < E_NUM; ++e) acc[e] += (double)vv[j] * (double)g[e];
        }
    }
#pragma unroll
    for (int e = 0; e < E_NUM; ++e) {
        double v = acc[e];
#pragma unroll
        for (int off = 32; off >= 1; off >>= 1) v += __shfl_xor(v, off);
        acc[e] = v;
    }
    if (lane == 0) {
        int s0 = 0;
#pragma unroll
        for (int e = 1; e < E_NUM; ++e) if (acc[e] > acc[s0]) s0 = e;
        int s1 = -1;
#pragma unroll
        for (int e = 0; e < E_NUM; ++e) if (e != s0 && (s1 < 0 || acc[e] > acc[s1])) s1 = e;
        float l0 = (float)acc[s0], l1 = (float)acc[s1];
        float p1 = __expf(l1 - l0);
        float inv = 1.0f / (1.0f + p1);
        int q0 = atomicAdd(&cnt[s0], 1);
        tok[s0 * CAP + q0] = t;  cf[s0 * CAP + q0] = inv;
        int q1 = atomicAdd(&cnt[s1], 1);
        tok[s1 * CAP + q1] = t;  cf[s1 * CAP + q1] = p1 * inv;
    }
}

// ---------------- prepass: w [E][K][N] fp32 -> wt [E][N][K] bf16 -----------
__global__ __launch_bounds__(256) void trw_kernel(const float* __restrict__ w,
                                                  unsigned short* __restrict__ wt,
                                                  int K, int N) {
    __shared__ float t[64][132];
    int e = blockIdx.z;
    int k0 = blockIdx.y * 64;
    int n0 = blockIdx.x * 128;
    const float* we = w + (size_t)e * K * N;
    unsigned short* wte = wt + (size_t)e * K * N;
    int tid = threadIdx.x;
    int rk = tid >> 5;
    int rn = (tid & 31) * 4;
#pragma unroll
    for (int p = 0; p < 8; ++p) {
        int k = rk + p * 8;
        float4 v = *(const float4*)(we + (size_t)(k0 + k) * N + n0 + rn);
        t[k][rn] = v.x; t[k][rn + 1] = v.y; t[k][rn + 2] = v.z; t[k][rn + 3] = v.w;
    }
    __syncthreads();
    int n = tid >> 1;
    int kc = (tid & 1) * 32;
    unsigned short* dst = wte + (size_t)(n0 + n) * K + k0 + kc;
#pragma unroll
    for (int c8 = 0; c8 < 4; ++c8) {
        u16x8 u;
#pragma unroll
        for (int c = 0; c < 8; ++c) u[c] = f2bf(t[kc + c8 * 8 + c][n]);
        *(u16x8*)(dst + c8 * 8) = u;
    }
}

// ================= GEMMs: depth-4 prefetch, 4 static buffers ===============
// LDS row = 32 bf16 = 4 chunks of 16B. LDS[r][c] holds global k-chunk c^(r&3).
// Staged via pre-swizzled per-lane SOURCE (#21); reads XOR the same pattern.

#define DECODE_SWZ(NBN_)                                                      \
    int total = E_NUM * NBM * (NBN_);                                         \
    int cpx = total >> 3;                                                     \
    int bid = blockIdx.x;                                                     \
    int swz = (bid & 7) * cpx + (bid >> 3);                                   \
    int e = swz / (NBM * (NBN_));                                             \
    int rem = swz - e * (NBM * (NBN_));                                       \
    int n_idx = rem / NBM;                                                    \
    int bm_idx = rem - n_idx * NBM;

__global__ __launch_bounds__(256, 2) void gemm1_fast(const unsigned short* __restrict__ xb,
                                                     const unsigned short* __restrict__ w1t,
                                                     const float* __restrict__ b1,
                                                     const int* __restrict__ cnt,
                                                     const int* __restrict__ tok,
                                                     unsigned short* __restrict__ Hbuf) {
    DECODE_SWZ(H_DIM / BN)
    int ne = cnt[e];
    int bm0 = bm_idx * BM;
    if (bm0 >= ne) return;
    int n0 = n_idx * BN;
    int offs = 0;
#pragma unroll
    for (int i = 0; i < E_NUM; ++i) offs += (i < e) ? cnt[i] : 0;

    __shared__ __align__(16) unsigned short As0[BM][BK], Bs0[BN][BK];
    __shared__ __align__(16) unsigned short As1[BM][BK], Bs1[BN][BK];
    __shared__ __align__(16) unsigned short As2[BM][BK], Bs2[BN][BK];
    __shared__ __align__(16) unsigned short As3[BM][BK], Bs3[BN][BK];
    __shared__ int s_tok[BM];

    int tid = threadIdx.x, lane = tid & 63, wv = tid >> 6;
    if (tid < BM) s_tok[tid] = tok[e * CAP + min(bm0 + tid, ne - 1)];

    int wr = (wv >> 1) * 64, wc = (wv & 1) * 64;
    int lm = lane & 15, lk = lane >> 4;
    // staging: per wave 2 A-loads + 2 B-loads; load l covers rows grp = wv*32+l*16,
    // lane -> row = grp + (lane>>2), chunk = lane&3; source chunk pre-swizzled.
    int srow = lane >> 2;
    int lk8s = (((lane & 3) ^ (srow & 3)) << 3);

    const unsigned short* w1e = w1t + (size_t)e * H_DIM * D_DIM;  // [n][k]

    __syncthreads();   // s_tok visible; vmcnt drained clean

    const unsigned short* gA[2];
    const unsigned short* gB[2];
#pragma unroll
    for (int l = 0; l < 2; ++l) {
        int row = wv * 32 + l * 16 + srow;
        gA[l] = xb + (size_t)s_tok[row] * D_DIM + lk8s;
        gB[l] = w1e + (size_t)(n0 + row) * D_DIM + lk8s;
    }

    f32x4 acc[4][4];
#pragma unroll
    for (int i = 0; i < 4; ++i)
#pragma unroll
        for (int j = 0; j < 4; ++j) { f32x4 z = {0.f, 0.f, 0.f, 0.f}; acc[i][j] = z; }

    auto STAGE = [&](unsigned short (&A)[BM][BK], unsigned short (&B)[BN][BK], int kb) {
        int k0 = kb * BK;
        gld_lds16(gA[0] + k0, &A[wv * 32 + 0][0]);
        gld_lds16(gA[1] + k0, &A[wv * 32 + 16][0]);
        gld_lds16(gB[0] + k0, &B[wv * 32 + 0][0]);
        gld_lds16(gB[1] + k0, &B[wv * 32 + 16][0]);
    };
    auto COMPUTE = [&](unsigned short (&A)[BM][BK], unsigned short (&B)[BN][BK]) {
        bf16x8 a[4], b[4];
        int kidx = ((lk ^ (lm & 3)) << 3);   // read-side swizzle (involution)
#pragma unroll
        for (int f = 0; f < 4; ++f) a[f] = *(const bf16x8*)&A[wr + f * 16 + lm][kidx];
#pragma unroll
        for (int f = 0; f < 4; ++f) b[f] = *(const bf16x8*)&B[wc + f * 16 + lm][kidx];
        __builtin_amdgcn_s_setprio(1);
#pragma unroll
        for (int i = 0; i < 4; ++i)
#pragma unroll
            for (int j = 0; j < 4; ++j)
                acc[i][j] = __builtin_amdgcn_mfma_f32_16x16x32_bf16(a[i], b[j], acc[i][j], 0, 0, 0);
        __builtin_amdgcn_s_setprio(0);
    };

    const int NT = D_DIM / BK;   // 32 (mult of 4)
    STAGE(As0, Bs0, 0);
    STAGE(As1, Bs1, 1);
    STAGE(As2, Bs2, 2);
    STAGE(As3, Bs3, 3);
    for (int t = 0; t < NT - 4; t += 4) {
        WAITV(12); SBAR; COMPUTE(As0, Bs0); SBAR; STAGE(As0, Bs0, t + 4);
        WAITV(12); SBAR; COMPUTE(As1, Bs1); SBAR; STAGE(As1, Bs1, t + 5);
        WAITV(12); SBAR; COMPUTE(As2, Bs2); SBAR; STAGE(As2, Bs2, t + 6);
        WAITV(12); SBAR; COMPUTE(As3, Bs3); SBAR; STAGE(As3, Bs3, t + 7);
    }
    WAITV(12); SBAR; COMPUTE(As0, Bs0); SBAR;
    WAITV(8);  SBAR; COMPUTE(As1, Bs1); SBAR;
    WAITV(4);  SBAR; COMPUTE(As2, Bs2); SBAR;
    WAITV(0);  SBAR; COMPUTE(As3, Bs3);

    const float* b1e = b1 + (size_t)e * H_DIM;
#pragma unroll
    for (int i = 0; i < 4; ++i) {
#pragma unroll
        for (int r = 0; r < 4; ++r) {
            int row = wr + i * 16 + lk * 4 + r;
            int gr = bm0 + row;
            if (gr >= ne) continue;
            size_t rb = (size_t)(offs + gr) * H_DIM;
#pragma unroll
            for (int j = 0; j < 4; ++j) {
                int gn = n0 + wc + j * 16 + lm;
                float v = acc[i][j][r] + b1e[gn];
                Hbuf[rb + gn] = f2bf(gelu_tanh(v));
            }
        }
    }
}

__global__ __launch_bounds__(256, 2) void gemm2_fast(const unsigned short* __restrict__ Hbuf,
                                                     const unsigned short* __restrict__ w2t,
                                                     const float* __restrict__ b2,
                                                     const int* __restrict__ cnt,
                                                     const int* __restrict__ tok,
                                                     const float* __restrict__ cf,
                                                     float* __restrict__ out) {
    DECODE_SWZ(D_DIM / BN)
    int ne = cnt[e];
    int bm0 = bm_idx * BM;
    if (bm0 >= ne) return;
    int n0 = n_idx * BN;
    int offs = 0;
#pragma unroll
    for (int i = 0; i < E_NUM; ++i) offs += (i < e) ? cnt[i] : 0;

    __shared__ __align__(16) unsigned short As0[BM][BK], Bs0[BN][BK];
    __shared__ __align__(16) unsigned short As1[BM][BK], Bs1[BN][BK];
    __shared__ __align__(16) unsigned short As2[BM][BK], Bs2[BN][BK];
    __shared__ __align__(16) unsigned short As3[BM][BK], Bs3[BN][BK];
    __shared__ int s_tok[BM];
    __shared__ float s_cf[BM];

    int tid = threadIdx.x, lane = tid & 63, wv = tid >> 6;
    if (tid < BM) {
        int gi = min(bm0 + tid, ne - 1);
        s_tok[tid] = tok[e * CAP + gi];
        s_cf[tid] = cf[e * CAP + gi];
    }

    int wr = (wv >> 1) * 64, wc = (wv & 1) * 64;
    int lm = lane & 15, lk = lane >> 4;
    int srow = lane >> 2;
    int lk8s = (((lane & 3) ^ (srow & 3)) << 3);

    const unsigned short* w2e = w2t + (size_t)e * H_DIM * D_DIM;  // [n][k]

    const unsigned short* gA[2];
    const unsigned short* gB[2];
#pragma unroll
    for (int l = 0; l < 2; ++l) {
        int row = wv * 32 + l * 16 + srow;
        gA[l] = Hbuf + (size_t)(offs + min(bm0 + row, ne - 1)) * H_DIM + lk8s;
        gB[l] = w2e + (size_t)(n0 + row) * H_DIM + lk8s;
    }

    f32x4 acc[4][4];
#pragma unroll
    for (int i = 0; i < 4; ++i)
#pragma unroll
        for (int j = 0; j < 4; ++j) { f32x4 z = {0.f, 0.f, 0.f, 0.f}; acc[i][j] = z; }

    auto STAGE = [&](unsigned short (&A)[BM][BK], unsigned short (&B)[BN][BK], int kb) {
        int k0 = kb * BK;
        gld_lds16(gA[0] + k0, &A[wv * 32 + 0][0]);
        gld_lds16(gA[1] + k0, &A[wv * 32 + 16][0]);
        gld_lds16(gB[0] + k0, &B[wv * 32 + 0][0]);
        gld_lds16(gB[1] + k0, &B[wv * 32 + 16][0]);
    };
    auto COMPUTE = [&](unsigned short (&A)[BM][BK], unsigned short (&B)[BN][BK]) {
        bf16x8 a[4], b[4];
        int kidx = ((lk ^ (lm & 3)) << 3);
#pragma unroll
        for (int f = 0; f < 4; ++f) a[f] = *(const bf16x8*)&A[wr + f * 16 + lm][kidx];
#pragma unroll
        for (int f = 0; f < 4; ++f) b[f] = *(const bf16x8*)&B[wc + f * 16 + lm][kidx];
        __builtin_amdgcn_s_setprio(1);
#pragma unroll
        for (int i = 0; i < 4; ++i)
#pragma unroll
            for (int j = 0; j < 4; ++j)
                acc[i][j] = __builtin_amdgcn_mfma_f32_16x16x32_bf16(a[i], b[j], acc[i][j], 0, 0, 0);
        __builtin_amdgcn_s_setprio(0);
    };

    __syncthreads();   // s_tok/s_cf visible; vmcnt drained clean

    const int NT = H_DIM / BK;   // 128 (mult of 4)
    STAGE(As0, Bs0, 0);
    STAGE(As1, Bs1, 1);
    STAGE(As2, Bs2, 2);
    STAGE(As3, Bs3, 3);
    for (int t = 0; t < NT - 4; t += 4) {
        WAITV(12); SBAR; COMPUTE(As0, Bs0); SBAR; STAGE(As0, Bs0, t + 4);
        WAITV(12); SBAR; COMPUTE(As1, Bs1); SBAR; STAGE(As1, Bs1, t + 5);
        WAITV(12); SBAR; COMPUTE(As2, Bs2); SBAR; STAGE(As2, Bs2, t + 6);
        WAITV(12); SBAR; COMPUTE(As3, Bs3); SBAR; STAGE(As3, Bs3, t + 7);
    }
    WAITV(12); SBAR; COMPUTE(As0, Bs0); SBAR;
    WAITV(8);  SBAR; COMPUTE(As1, Bs1); SBAR;
    WAITV(4);  SBAR; COMPUTE(As2, Bs2); SBAR;
    WAITV(0);  SBAR; COMPUTE(As3, Bs3);

    const float* b2e = b2 + (size_t)e * D_DIM;
#pragma unroll
    for (int i = 0; i < 4; ++i) {
#pragma unroll
        for (int r = 0; r < 4; ++r) {
            int row = wr + i * 16 + lk * 4 + r;
            int gr = bm0 + row;
            if (gr >= ne) continue;
            int tk = s_tok[row];
            float w = s_cf[row];
#pragma unroll
            for (int j = 0; j < 4; ++j) {
                int gn = n0 + wc + j * 16 + lm;
                float y = acc[i][j][r] + b2e[gn];
                atomicAdd(&out[(size_t)tk * D_DIM + gn], w * y);
            }
        }
    }
}

extern "C" void kernel_launch(void* const* d_in, const int* in_sizes, int n_in,
                              void* d_out, int out_size, void* d_ws, size_t ws_size,
                              hipStream_t stream) {
    const float* x  = (const float*)d_in[0];
    const float* gw = (const float*)d_in[1];
    const float* w1 = (const float*)d_in[2];
    const float* b1 = (const float*)d_in[3];
    const float* w2 = (const float*)d_in[4];
    const float* b2 = (const float*)d_in[5];
    float* out = (float*)d_out;

    char* ws = (char*)d_ws;
    const size_t SZ_ROUTE = 256 + (size_t)2 * E_NUM * CAP * 4;
    const size_t SZ_XB    = (size_t)T_TOKENS * D_DIM * 2;
    const size_t SZ_W     = (size_t)E_NUM * D_DIM * H_DIM * 2;
    const size_t SZ_H     = (size_t)2 * T_TOKENS * H_DIM * 2;

    int*   cnt = (int*)ws;
    int*   tok = (int*)(ws + 256);
    float* cff = (float*)(ws + 256 + E_NUM * CAP * 4);

    size_t need_fast = SZ_ROUTE + SZ_XB + 2 * SZ_W + SZ_H;
    if (ws_size < need_fast) return;  // loud failure: out stays poisoned

    unsigned short* xb   = (unsigned short*)(ws + SZ_ROUTE);
    unsigned short* w1t  = (unsigned short*)(ws + SZ_ROUTE + SZ_XB);
    unsigned short* w2t  = (unsigned short*)(ws + SZ_ROUTE + SZ_XB + SZ_W);
    unsigned short* Hbuf = (unsigned short*)(ws + SZ_ROUTE + SZ_XB + 2 * SZ_W);

    hipMemsetAsync(cnt, 0, E_NUM * sizeof(int), stream);
    hipMemsetAsync(out, 0, (size_t)out_size * sizeof(float), stream);

    gate_kernel<<<T_TOKENS / 4, 256, 0, stream>>>(x, gw, cnt, tok, cff, xb);

    dim3 gt1(H_DIM / 128, D_DIM / 64, E_NUM);
    trw_kernel<<<gt1, 256, 0, stream>>>(w1, w1t, D_DIM, H_DIM);
    dim3 gt2(D_DIM / 128, H_DIM / 64, E_NUM);
    trw_kernel<<<gt2, 256, 0, stream>>>(w2, w2t, H_DIM, D_DIM);

    gemm1_fast<<<E_NUM * NBM * (H_DIM / BN), 256, 0, stream>>>(xb, w1t, b1, cnt, tok, Hbuf);
    gemm2_fast<<<E_NUM * NBM * (D_DIM / BN), 256, 0, stream>>>(Hbuf, w2t, b2, cnt, tok, cff, out);
}

// Round 7
// 834.758 us; speedup vs baseline: 1.8827x; 1.0612x over previous
//
#include <hip/hip_runtime.h>
#include <hip/hip_bf16.h>

#define T_TOKENS 8192
#define D_DIM 1024
#define H_DIM 4096
#define E_NUM 8
#define CAP 8192
#define BM 256           // rows per block-tile
#define BN 128           // cols per block-tile
#define BK 32            // K per LDS buffer (2 buffers, depth-2)
#define NSLOT 8          // bm grid-stride slots

typedef short bf16x8 __attribute__((ext_vector_type(8)));
typedef float f32x4 __attribute__((ext_vector_type(4)));
typedef unsigned short u16x8 __attribute__((ext_vector_type(8)));

__device__ inline unsigned short f2bf(float f) {
    union { float f; unsigned int u; } v; v.f = f;
    unsigned int u = v.u;
    return (unsigned short)((u + 0x7fffu + ((u >> 16) & 1u)) >> 16);  // RNE
}

__device__ inline float gelu_tanh(float v) {
    float c = 0.7978845608028654f * (v + 0.044715f * v * v * v);
    float t = 1.0f - 2.0f / (__expf(2.0f * c) + 1.0f);   // tanh(c)
    return 0.5f * v * (1.0f + t);
}

// async global->LDS, 16B/lane; lds base wave-uniform (HW adds lane*16)
__device__ inline void gld_lds16(const unsigned short* g, unsigned short* lds) {
    __builtin_amdgcn_global_load_lds(
        (const __attribute__((address_space(1))) void*)g,
        (__attribute__((address_space(3))) void*)lds, 16, 0, 0);
}

// counted waits + raw barrier (rule 18: pin with sched_barrier(0))
#define WAITV(N) do { asm volatile("s_waitcnt vmcnt(" #N ")" ::: "memory"); \
                      __builtin_amdgcn_sched_barrier(0); } while (0)
#define SBAR     do { __builtin_amdgcn_sched_barrier(0); \
                      __builtin_amdgcn_s_barrier(); \
                      __builtin_amdgcn_sched_barrier(0); } while (0)

// ---------------- gate (+ fused x fp32->bf16 conversion) -------------------
__global__ __launch_bounds__(256) void gate_kernel(const float* __restrict__ x,
                                                   const float* __restrict__ gw,
                                                   int* __restrict__ cnt,
                                                   int* __restrict__ tok,
                                                   float* __restrict__ cf,
                                                   unsigned short* __restrict__ xb) {
    int lane = threadIdx.x & 63;
    int t = blockIdx.x * 4 + (threadIdx.x >> 6);
    const float* xr = x + (size_t)t * D_DIM;
    unsigned short* xbr = xb + (size_t)t * D_DIM;
    double acc[E_NUM];
#pragma unroll
    for (int e = 0; e < E_NUM; ++e) acc[e] = 0.0;
#pragma unroll
    for (int it = 0; it < 4; ++it) {
        int d = it * 256 + lane * 4;
        float4 v = *(const float4*)(xr + d);
        ushort4 u;
        u.x = f2bf(v.x); u.y = f2bf(v.y); u.z = f2bf(v.z); u.w = f2bf(v.w);
        *(ushort4*)(xbr + d) = u;
        const float vv[4] = {v.x, v.y, v.z, v.w};
#pragma unroll
        for (int j = 0; j < 4; ++j) {
            const float* g = gw + (size_t)(d + j) * E_NUM;
#pragma unroll
            for (int e = 0; e < E_NUM; ++e) acc[e] += (double)vv[j] * (double)g[e];
        }
    }
#pragma unroll
    for (int e = 0; e < E_NUM; ++e) {
        double v = acc[e];
#pragma unroll
        for (int off = 32; off >= 1; off >>= 1) v += __shfl_xor(v, off);
        acc[e] = v;
    }
    if (lane == 0) {
        int s0 = 0;
#pragma unroll
        for (int e = 1; e < E_NUM; ++e) if (acc[e] > acc[s0]) s0 = e;
        int s1 = -1;
#pragma unroll
        for (int e = 0; e < E_NUM; ++e) if (e != s0 && (s1 < 0 || acc[e] > acc[s1])) s1 = e;
        float l0 = (float)acc[s0], l1 = (float)acc[s1];
        float p1 = __expf(l1 - l0);
        float inv = 1.0f / (1.0f + p1);
        int q0 = atomicAdd(&cnt[s0], 1);
        tok[s0 * CAP + q0] = t;  cf[s0 * CAP + q0] = inv;
        int q1 = atomicAdd(&cnt[s1], 1);
        tok[s1 * CAP + q1] = t;  cf[s1 * CAP + q1] = p1 * inv;
    }
}

// ---------------- prepass: w [E][K][N] fp32 -> wt [E][N][K] bf16 -----------
__global__ __launch_bounds__(256) void trw_kernel(const float* __restrict__ w,
                                                  unsigned short* __restrict__ wt,
                                                  int K, int N) {
    __shared__ float t[64][132];
    int e = blockIdx.z;
    int k0 = blockIdx.y * 64;
    int n0 = blockIdx.x * 128;
    const float* we = w + (size_t)e * K * N;
    unsigned short* wte = wt + (size_t)e * K * N;
    int tid = threadIdx.x;
    int rk = tid >> 5;
    int rn = (tid & 31) * 4;
#pragma unroll
    for (int p = 0; p < 8; ++p) {
        int k = rk + p * 8;
        float4 v = *(const float4*)(we + (size_t)(k0 + k) * N + n0 + rn);
        t[k][rn] = v.x; t[k][rn + 1] = v.y; t[k][rn + 2] = v.z; t[k][rn + 3] = v.w;
    }
    __syncthreads();
    int n = tid >> 1;
    int kc = (tid & 1) * 32;
    unsigned short* dst = wte + (size_t)(n0 + n) * K + k0 + kc;
#pragma unroll
    for (int c8 = 0; c8 < 4; ++c8) {
        u16x8 u;
#pragma unroll
        for (int c = 0; c < 8; ++c) u[c] = f2bf(t[kc + c8 * 8 + c][n]);
        *(u16x8*)(dst + c8 * 8) = u;
    }
}

// ================= GEMMs: 256x128 tile, 128x64/wave, depth-2 pipeline ======
// LDS row = 32 bf16 = 4 chunks of 16B; LDS[r][c] holds global chunk c^(r&3).
// Staged via pre-swizzled per-lane SOURCE; reads XOR the same involution.

__global__ __launch_bounds__(256, 2) void gemm1_fast(const unsigned short* __restrict__ xb,
                                                     const unsigned short* __restrict__ w1t,
                                                     const float* __restrict__ b1,
                                                     const int* __restrict__ cnt,
                                                     const int* __restrict__ tok,
                                                     unsigned short* __restrict__ Hbuf) {
    // grid = E * (H/BN=32) * NSLOT = 2048, XCD-chunked, slot fastest
    int bid = blockIdx.x;
    int swz = (bid & 7) * 256 + (bid >> 3);
    int e = swz >> 8;
    int n_idx = (swz >> 3) & 31;
    int slot = swz & 7;
    int ne = cnt[e];
    int n0 = n_idx * BN;
    int offs = 0;
#pragma unroll
    for (int i = 0; i < E_NUM; ++i) offs += (i < e) ? cnt[i] : 0;

    __shared__ __align__(16) unsigned short As0[BM][BK], As1[BM][BK];
    __shared__ __align__(16) unsigned short Bs0[BN][BK], Bs1[BN][BK];
    __shared__ int s_tok[BM];

    int tid = threadIdx.x, lane = tid & 63, wv = tid >> 6;
    int wr = (wv >> 1) * 128, wc = (wv & 1) * 64;
    int lm = lane & 15, lk = lane >> 4;
    int srow = lane >> 2;                                // staging row-in-16
    int schunk = (((lane & 3) ^ (srow & 3)) << 3);       // pre-swizzled src k-off
    int kidx = ((lk ^ (lm & 3)) << 3);                   // read-side swizzle

    const unsigned short* w1e = w1t + (size_t)e * H_DIM * D_DIM;  // [n][k]
    const float* b1e = b1 + (size_t)e * H_DIM;
    float bias_v[4];
#pragma unroll
    for (int j = 0; j < 4; ++j) bias_v[j] = b1e[n0 + wc + j * 16 + lm];

    for (int bm0 = slot * BM; bm0 < ne; bm0 += NSLOT * BM) {
        s_tok[tid] = tok[e * CAP + min(bm0 + tid, ne - 1)];
        __syncthreads();   // publish s_tok; drains vmcnt (incl. prev epilogue)

        const unsigned short* gA[4];
        const unsigned short* gB[2];
#pragma unroll
        for (int l = 0; l < 4; ++l)
            gA[l] = xb + (size_t)s_tok[wv * 64 + l * 16 + srow] * D_DIM + schunk;
#pragma unroll
        for (int l = 0; l < 2; ++l)
            gB[l] = w1e + (size_t)(n0 + wv * 32 + l * 16 + srow) * D_DIM + schunk;

        f32x4 acc[8][4];
#pragma unroll
        for (int i = 0; i < 8; ++i)
#pragma unroll
            for (int j = 0; j < 4; ++j) { f32x4 z = {0.f, 0.f, 0.f, 0.f}; acc[i][j] = z; }

        auto STAGE = [&](unsigned short (&A)[BM][BK], unsigned short (&B)[BN][BK], int kb) {
            int k0 = kb * BK;
#pragma unroll
            for (int l = 0; l < 4; ++l) gld_lds16(gA[l] + k0, &A[wv * 64 + l * 16][0]);
#pragma unroll
            for (int l = 0; l < 2; ++l) gld_lds16(gB[l] + k0, &B[wv * 32 + l * 16][0]);
        };
        auto COMPUTE = [&](unsigned short (&A)[BM][BK], unsigned short (&B)[BN][BK]) {
            bf16x8 b[4], a[8];
#pragma unroll
            for (int f = 0; f < 4; ++f) b[f] = *(const bf16x8*)&B[wc + f * 16 + lm][kidx];
#pragma unroll
            for (int f = 0; f < 8; ++f) a[f] = *(const bf16x8*)&A[wr + f * 16 + lm][kidx];
            __builtin_amdgcn_s_setprio(1);
#pragma unroll
            for (int i = 0; i < 8; ++i)
#pragma unroll
                for (int j = 0; j < 4; ++j)
                    acc[i][j] = __builtin_amdgcn_mfma_f32_16x16x32_bf16(a[i], b[j], acc[i][j], 0, 0, 0);
            __builtin_amdgcn_s_setprio(0);
        };

        const int NT = D_DIM / BK;   // 32 (even, >=4)
        STAGE(As0, Bs0, 0);
        STAGE(As1, Bs1, 1);
        for (int t = 0; t < NT - 2; t += 2) {
            WAITV(6); SBAR; COMPUTE(As0, Bs0); SBAR; STAGE(As0, Bs0, t + 2);
            WAITV(6); SBAR; COMPUTE(As1, Bs1); SBAR; STAGE(As1, Bs1, t + 3);
        }
        WAITV(6); SBAR; COMPUTE(As0, Bs0); SBAR;
        WAITV(0); SBAR; COMPUTE(As1, Bs1);

#pragma unroll
        for (int i = 0; i < 8; ++i) {
#pragma unroll
            for (int r = 0; r < 4; ++r) {
                int row = wr + i * 16 + lk * 4 + r;
                int gr = bm0 + row;
                if (gr >= ne) continue;
                size_t rb = (size_t)(offs + gr) * H_DIM;
#pragma unroll
                for (int j = 0; j < 4; ++j) {
                    int gn = n0 + wc + j * 16 + lm;
                    float v = acc[i][j][r] + bias_v[j];
                    Hbuf[rb + gn] = f2bf(gelu_tanh(v));
                }
            }
        }
        __syncthreads();  // all waves done before next iter rewrites s_tok/LDS
    }
}

__global__ __launch_bounds__(256, 2) void gemm2_fast(const unsigned short* __restrict__ Hbuf,
                                                     const unsigned short* __restrict__ w2t,
                                                     const float* __restrict__ b2,
                                                     const int* __restrict__ cnt,
                                                     const int* __restrict__ tok,
                                                     const float* __restrict__ cf,
                                                     float* __restrict__ out) {
    // grid = E * (D/BN=8) * NSLOT = 512, XCD-chunked, slot fastest
    int bid = blockIdx.x;
    int swz = (bid & 7) * 64 + (bid >> 3);
    int e = swz >> 6;
    int n_idx = (swz >> 3) & 7;
    int slot = swz & 7;
    int ne = cnt[e];
    int n0 = n_idx * BN;
    int offs = 0;
#pragma unroll
    for (int i = 0; i < E_NUM; ++i) offs += (i < e) ? cnt[i] : 0;

    __shared__ __align__(16) unsigned short As0[BM][BK], As1[BM][BK];
    __shared__ __align__(16) unsigned short Bs0[BN][BK], Bs1[BN][BK];
    __shared__ int s_tok[BM];
    __shared__ float s_cf[BM];

    int tid = threadIdx.x, lane = tid & 63, wv = tid >> 6;
    int wr = (wv >> 1) * 128, wc = (wv & 1) * 64;
    int lm = lane & 15, lk = lane >> 4;
    int srow = lane >> 2;
    int schunk = (((lane & 3) ^ (srow & 3)) << 3);
    int kidx = ((lk ^ (lm & 3)) << 3);

    const unsigned short* w2e = w2t + (size_t)e * H_DIM * D_DIM;  // [n][k]
    const float* b2e = b2 + (size_t)e * D_DIM;
    float bias_v[4];
#pragma unroll
    for (int j = 0; j < 4; ++j) bias_v[j] = b2e[n0 + wc + j * 16 + lm];

    for (int bm0 = slot * BM; bm0 < ne; bm0 += NSLOT * BM) {
        int gi = min(bm0 + tid, ne - 1);
        s_tok[tid] = tok[e * CAP + gi];
        s_cf[tid] = cf[e * CAP + gi];
        __syncthreads();   // publish; drains vmcnt (incl. prev epilogue atomics)

        const unsigned short* gA[4];
        const unsigned short* gB[2];
#pragma unroll
        for (int l = 0; l < 4; ++l)
            gA[l] = Hbuf + (size_t)(offs + min(bm0 + wv * 64 + l * 16 + srow, ne - 1)) * H_DIM + schunk;
#pragma unroll
        for (int l = 0; l < 2; ++l)
            gB[l] = w2e + (size_t)(n0 + wv * 32 + l * 16 + srow) * H_DIM + schunk;

        f32x4 acc[8][4];
#pragma unroll
        for (int i = 0; i < 8; ++i)
#pragma unroll
            for (int j = 0; j < 4; ++j) { f32x4 z = {0.f, 0.f, 0.f, 0.f}; acc[i][j] = z; }

        auto STAGE = [&](unsigned short (&A)[BM][BK], unsigned short (&B)[BN][BK], int kb) {
            int k0 = kb * BK;
#pragma unroll
            for (int l = 0; l < 4; ++l) gld_lds16(gA[l] + k0, &A[wv * 64 + l * 16][0]);
#pragma unroll
            for (int l = 0; l < 2; ++l) gld_lds16(gB[l] + k0, &B[wv * 32 + l * 16][0]);
        };
        auto COMPUTE = [&](unsigned short (&A)[BM][BK], unsigned short (&B)[BN][BK]) {
            bf16x8 b[4], a[8];
#pragma unroll
            for (int f = 0; f < 4; ++f) b[f] = *(const bf16x8*)&B[wc + f * 16 + lm][kidx];
#pragma unroll
            for (int f = 0; f < 8; ++f) a[f] = *(const bf16x8*)&A[wr + f * 16 + lm][kidx];
            __builtin_amdgcn_s_setprio(1);
#pragma unroll
            for (int i = 0; i < 8; ++i)
#pragma unroll
                for (int j = 0; j < 4; ++j)
                    acc[i][j] = __builtin_amdgcn_mfma_f32_16x16x32_bf16(a[i], b[j], acc[i][j], 0, 0, 0);
            __builtin_amdgcn_s_setprio(0);
        };

        const int NT = H_DIM / BK;   // 128 (even, >=4)
        STAGE(As0, Bs0, 0);
        STAGE(As1, Bs1, 1);
        for (int t = 0; t < NT - 2; t += 2) {
            WAITV(6); SBAR; COMPUTE(As0, Bs0); SBAR; STAGE(As0, Bs0, t + 2);
            WAITV(6); SBAR; COMPUTE(As1, Bs1); SBAR; STAGE(As1, Bs1, t + 3);
        }
        WAITV(6); SBAR; COMPUTE(As0, Bs0); SBAR;
        WAITV(0); SBAR; COMPUTE(As1, Bs1);

#pragma unroll
        for (int i = 0; i < 8; ++i) {
#pragma unroll
            for (int r = 0; r < 4; ++r) {
                int row = wr + i * 16 + lk * 4 + r;
                int gr = bm0 + row;
                if (gr >= ne) continue;
                int tk = s_tok[row];
                float w = s_cf[row];
#pragma unroll
                for (int j = 0; j < 4; ++j) {
                    int gn = n0 + wc + j * 16 + lm;
                    float y = acc[i][j][r] + bias_v[j];
                    atomicAdd(&out[(size_t)tk * D_DIM + gn], w * y);
                }
            }
        }
        __syncthreads();  // all waves done before next iter rewrites s_tok/LDS
    }
}

extern "C" void kernel_launch(void* const* d_in, const int* in_sizes, int n_in,
                              void* d_out, int out_size, void* d_ws, size_t ws_size,
                              hipStream_t stream) {
    const float* x  = (const float*)d_in[0];
    const float* gw = (const float*)d_in[1];
    const float* w1 = (const float*)d_in[2];
    const float* b1 = (const float*)d_in[3];
    const float* w2 = (const float*)d_in[4];
    const float* b2 = (const float*)d_in[5];
    float* out = (float*)d_out;

    char* ws = (char*)d_ws;
    const size_t SZ_ROUTE = 256 + (size_t)2 * E_NUM * CAP * 4;
    const size_t SZ_XB    = (size_t)T_TOKENS * D_DIM * 2;
    const size_t SZ_W     = (size_t)E_NUM * D_DIM * H_DIM * 2;
    const size_t SZ_H     = (size_t)2 * T_TOKENS * H_DIM * 2;

    int*   cnt = (int*)ws;
    int*   tok = (int*)(ws + 256);
    float* cff = (float*)(ws + 256 + E_NUM * CAP * 4);

    size_t need_fast = SZ_ROUTE + SZ_XB + 2 * SZ_W + SZ_H;
    if (ws_size < need_fast) return;  // loud failure: out stays poisoned

    unsigned short* xb   = (unsigned short*)(ws + SZ_ROUTE);
    unsigned short* w1t  = (unsigned short*)(ws + SZ_ROUTE + SZ_XB);
    unsigned short* w2t  = (unsigned short*)(ws + SZ_ROUTE + SZ_XB + SZ_W);
    unsigned short* Hbuf = (unsigned short*)(ws + SZ_ROUTE + SZ_XB + 2 * SZ_W);

    hipMemsetAsync(cnt, 0, E_NUM * sizeof(int), stream);
    hipMemsetAsync(out, 0, (size_t)out_size * sizeof(float), stream);

    gate_kernel<<<T_TOKENS / 4, 256, 0, stream>>>(x, gw, cnt, tok, cff, xb);

    dim3 gt1(H_DIM / 128, D_DIM / 64, E_NUM);
    trw_kernel<<<gt1, 256, 0, stream>>>(w1, w1t, D_DIM, H_DIM);
    dim3 gt2(D_DIM / 128, H_DIM / 64, E_NUM);
    trw_kernel<<<gt2, 256, 0, stream>>>(w2, w2t, H_DIM, D_DIM);

    gemm1_fast<<<E_NUM * (H_DIM / BN) * NSLOT, 256, 0, stream>>>(xb, w1t, b1, cnt, tok, Hbuf);
    gemm2_fast<<<E_NUM * (D_DIM / BN) * NSLOT, 256, 0, stream>>>(Hbuf, w2t, b2, cnt, tok, cff, out);
}

// Round 8
// 744.858 us; speedup vs baseline: 2.1099x; 1.1207x over previous
//
#include <hip/hip_runtime.h>
#include <hip/hip_bf16.h>

#define T_TOKENS 8192
#define D_DIM 1024
#define H_DIM 4096
#define E_NUM 8
#define CAP 8192

typedef short bf16x8 __attribute__((ext_vector_type(8)));
typedef float f32x4 __attribute__((ext_vector_type(4)));
typedef unsigned short u16x8 __attribute__((ext_vector_type(8)));

__device__ inline unsigned short f2bf(float f) {
    union { float f; unsigned int u; } v; v.f = f;
    unsigned int u = v.u;
    return (unsigned short)((u + 0x7fffu + ((u >> 16) & 1u)) >> 16);  // RNE
}

__device__ inline float gelu_tanh(float v) {
    float c = 0.7978845608028654f * (v + 0.044715f * v * v * v);
    float t = 1.0f - 2.0f / (__expf(2.0f * c) + 1.0f);   // tanh(c)
    return 0.5f * v * (1.0f + t);
}

// async global->LDS, 16B/lane; lds base wave-uniform (HW adds lane*16)
__device__ inline void gld_lds16(const unsigned short* g, unsigned short* lds) {
    __builtin_amdgcn_global_load_lds(
        (const __attribute__((address_space(1))) void*)g,
        (__attribute__((address_space(3))) void*)lds, 16, 0, 0);
}

#define WAITV0 do { asm volatile("s_waitcnt vmcnt(0)" ::: "memory"); \
                    __builtin_amdgcn_sched_barrier(0); } while (0)
#define SBAR   do { __builtin_amdgcn_sched_barrier(0); \
                    __builtin_amdgcn_s_barrier(); \
                    __builtin_amdgcn_sched_barrier(0); } while (0)

// ---------------- gate (+ fused x fp32->bf16 conversion) -------------------
__global__ __launch_bounds__(256) void gate_kernel(const float* __restrict__ x,
                                                   const float* __restrict__ gw,
                                                   int* __restrict__ cnt,
                                                   int* __restrict__ tok,
                                                   float* __restrict__ cf,
                                                   unsigned short* __restrict__ xb) {
    int lane = threadIdx.x & 63;
    int t = blockIdx.x * 4 + (threadIdx.x >> 6);
    const float* xr = x + (size_t)t * D_DIM;
    unsigned short* xbr = xb + (size_t)t * D_DIM;
    double acc[E_NUM];
#pragma unroll
    for (int e = 0; e < E_NUM; ++e) acc[e] = 0.0;
#pragma unroll
    for (int it = 0; it < 4; ++it) {
        int d = it * 256 + lane * 4;
        float4 v = *(const float4*)(xr + d);
        ushort4 u;
        u.x = f2bf(v.x); u.y = f2bf(v.y); u.z = f2bf(v.z); u.w = f2bf(v.w);
        *(ushort4*)(xbr + d) = u;
        const float vv[4] = {v.x, v.y, v.z, v.w};
#pragma unroll
        for (int j = 0; j < 4; ++j) {
            const float* g = gw + (size_t)(d + j) * E_NUM;
#pragma unroll
            for (int e = 0; e < E_NUM; ++e) acc[e] += (double)vv[j] * (double)g[e];
        }
    }
#pragma unroll
    for (int e = 0; e < E_NUM; ++e) {
        double v = acc[e];
#pragma unroll
        for (int off = 32; off >= 1; off >>= 1) v += __shfl_xor(v, off);
        acc[e] = v;
    }
    if (lane == 0) {
        int s0 = 0;
#pragma unroll
        for (int e = 1; e < E_NUM; ++e) if (acc[e] > acc[s0]) s0 = e;
        int s1 = -1;
#pragma unroll
        for (int e = 0; e < E_NUM; ++e) if (e != s0 && (s1 < 0 || acc[e] > acc[s1])) s1 = e;
        float l0 = (float)acc[s0], l1 = (float)acc[s1];
        float p1 = __expf(l1 - l0);
        float inv = 1.0f / (1.0f + p1);
        int q0 = atomicAdd(&cnt[s0], 1);
        tok[s0 * CAP + q0] = t;  cf[s0 * CAP + q0] = inv;
        int q1 = atomicAdd(&cnt[s1], 1);
        tok[s1 * CAP + q1] = t;  cf[s1 * CAP + q1] = p1 * inv;
    }
}

// ---------------- prepass: w [E][K][N] fp32 -> wt [E][N][K] bf16 -----------
__global__ __launch_bounds__(256) void trw_kernel(const float* __restrict__ w,
                                                  unsigned short* __restrict__ wt,
                                                  int K, int N) {
    __shared__ float t[64][132];
    int e = blockIdx.z;
    int k0 = blockIdx.y * 64;
    int n0 = blockIdx.x * 128;
    const float* we = w + (size_t)e * K * N;
    unsigned short* wte = wt + (size_t)e * K * N;
    int tid = threadIdx.x;
    int rk = tid >> 5;
    int rn = (tid & 31) * 4;
#pragma unroll
    for (int p = 0; p < 8; ++p) {
        int k = rk + p * 8;
        float4 v = *(const float4*)(we + (size_t)(k0 + k) * N + n0 + rn);
        t[k][rn] = v.x; t[k][rn + 1] = v.y; t[k][rn + 2] = v.z; t[k][rn + 3] = v.w;
    }
    __syncthreads();
    int n = tid >> 1;
    int kc = (tid & 1) * 32;
    unsigned short* dst = wte + (size_t)(n0 + n) * K + k0 + kc;
#pragma unroll
    for (int c8 = 0; c8 < 4; ++c8) {
        u16x8 u;
#pragma unroll
        for (int c = 0; c < 8; ++c) u[c] = f2bf(t[kc + c8 * 8 + c][n]);
        *(u16x8*)(dst + c8 * 8) = u;
    }
}

// ================= GEMM1: 128x128 tile, BK=64, flat items, 1-barrier/tile ==
// LDS row = 64 bf16 = 8 chunks of 16B; LDS[r][c] holds global chunk c^(r&7).
// Staged via pre-swizzled per-lane SOURCE; reads XOR the same involution.

__global__ __launch_bounds__(256, 2) void gemm1_fast(const unsigned short* __restrict__ xb,
                                                     const unsigned short* __restrict__ w1t,
                                                     const float* __restrict__ b1,
                                                     const int* __restrict__ cnt,
                                                     const int* __restrict__ tok,
                                                     unsigned short* __restrict__ Hbuf) {
    __shared__ __align__(16) unsigned short As0[128][64], As1[128][64];
    __shared__ __align__(16) unsigned short Bs0[128][64], Bs1[128][64];
    __shared__ int s_tok[128];

    int tid = threadIdx.x, lane = tid & 63, wv = tid >> 6;
    int wr = (wv >> 1) * 64, wc = (wv & 1) * 64;
    int lm = lane & 15, lk = lane >> 4;
    int srow = lane >> 3;                       // row-in-8 for staging
    int schunk = ((lane & 7) ^ srow) << 3;      // pre-swizzled source k-offset

    int ne_[E_NUM], offs_[E_NUM], pref[E_NUM + 1];
    pref[0] = 0;
    int off = 0;
#pragma unroll
    for (int e = 0; e < E_NUM; ++e) {
        ne_[e] = cnt[e];
        offs_[e] = off; off += ne_[e];
        pref[e + 1] = pref[e] + ((ne_[e] + 127) >> 7) * 32;   // nbm * 32 n-tiles
    }
    int T = pref[E_NUM];

    for (int w = blockIdx.x; w < T; w += gridDim.x) {
        int e = 0;
#pragma unroll
        for (int q = 0; q < E_NUM - 1; ++q) e += (w >= pref[q + 1]) ? 1 : 0;
        int local = w - pref[e];
        int bm0 = (local >> 5) * 128;
        int n0 = (local & 31) * 128;
        int ne = ne_[e];
        int offs = offs_[e];
        const unsigned short* w1e = w1t + (size_t)e * H_DIM * D_DIM;  // [n][k]

        __syncthreads();     // prev item fully done (incl. s_tok readers)
        if (tid < 128) s_tok[tid] = tok[e * CAP + min(bm0 + tid, ne - 1)];
        __syncthreads();     // publish s_tok

        const unsigned short* gA[4];
        const unsigned short* gB[4];
#pragma unroll
        for (int l = 0; l < 4; ++l) {
            gA[l] = xb + (size_t)s_tok[wv * 32 + l * 8 + srow] * D_DIM + schunk;
            gB[l] = w1e + (size_t)(n0 + wv * 32 + l * 8 + srow) * D_DIM + schunk;
        }
        float bias_v[4];
#pragma unroll
        for (int j = 0; j < 4; ++j) bias_v[j] = b1[(size_t)e * H_DIM + n0 + wc + j * 16 + lm];

        f32x4 acc[4][4];
#pragma unroll
        for (int i = 0; i < 4; ++i)
#pragma unroll
            for (int j = 0; j < 4; ++j) { f32x4 z = {0.f, 0.f, 0.f, 0.f}; acc[i][j] = z; }

        auto STAGE = [&](unsigned short (&A)[128][64], unsigned short (&B)[128][64], int kb) {
            int k0 = kb * 64;
#pragma unroll
            for (int l = 0; l < 4; ++l) gld_lds16(gA[l] + k0, &A[wv * 32 + l * 8][0]);
#pragma unroll
            for (int l = 0; l < 4; ++l) gld_lds16(gB[l] + k0, &B[wv * 32 + l * 8][0]);
        };
        auto COMPUTE = [&](unsigned short (&A)[128][64], unsigned short (&B)[128][64]) {
#pragma unroll
            for (int ks = 0; ks < 2; ++ks) {
                bf16x8 a[4], b[4];
                int c = (((ks * 4 + lk) ^ (lm & 7)) << 3);   // swizzled read chunk
#pragma unroll
                for (int f = 0; f < 4; ++f) a[f] = *(const bf16x8*)&A[wr + f * 16 + lm][c];
#pragma unroll
                for (int f = 0; f < 4; ++f) b[f] = *(const bf16x8*)&B[wc + f * 16 + lm][c];
                __builtin_amdgcn_s_setprio(1);
#pragma unroll
                for (int i = 0; i < 4; ++i)
#pragma unroll
                    for (int j = 0; j < 4; ++j)
                        acc[i][j] = __builtin_amdgcn_mfma_f32_16x16x32_bf16(a[i], b[j], acc[i][j], 0, 0, 0);
                __builtin_amdgcn_s_setprio(0);
            }
        };

        const int NT = D_DIM / 64;   // 16
        STAGE(As0, Bs0, 0);
        WAITV0; SBAR;
        for (int t = 0; t < NT; t += 2) {
            if (t + 1 < NT) STAGE(As1, Bs1, t + 1);   // issue BEFORE compute
            COMPUTE(As0, Bs0);
            WAITV0; SBAR;                              // stage done; one barrier/tile
            if (t + 2 < NT) STAGE(As0, Bs0, t + 2);
            COMPUTE(As1, Bs1);
            WAITV0; SBAR;
        }

#pragma unroll
        for (int i = 0; i < 4; ++i) {
#pragma unroll
            for (int r = 0; r < 4; ++r) {
                int row = wr + i * 16 + lk * 4 + r;
                int gr = bm0 + row;
                if (gr >= ne) continue;
                size_t rb = (size_t)(offs + gr) * H_DIM;
#pragma unroll
                for (int j = 0; j < 4; ++j) {
                    int gn = n0 + wc + j * 16 + lm;
                    float v = acc[i][j][r] + bias_v[j];
                    Hbuf[rb + gn] = f2bf(gelu_tanh(v));
                }
            }
        }
    }
}

// ================= GEMM2: 128x64 tile, BK=64, 3 blocks/CU, flat items ======
__global__ __launch_bounds__(256, 3) void gemm2_fast(const unsigned short* __restrict__ Hbuf,
                                                     const unsigned short* __restrict__ w2t,
                                                     const float* __restrict__ b2,
                                                     const int* __restrict__ cnt,
                                                     const int* __restrict__ tok,
                                                     const float* __restrict__ cf,
                                                     float* __restrict__ out) {
    __shared__ __align__(16) unsigned short As0[128][64], As1[128][64];
    __shared__ __align__(16) unsigned short Bs0[64][64], Bs1[64][64];
    __shared__ int s_tok[128];
    __shared__ float s_cf[128];

    int tid = threadIdx.x, lane = tid & 63, wv = tid >> 6;
    int wr = (wv >> 1) * 64, wc = (wv & 1) * 32;
    int lm = lane & 15, lk = lane >> 4;
    int srow = lane >> 3;
    int schunk = ((lane & 7) ^ srow) << 3;

    int ne_[E_NUM], offs_[E_NUM], pref[E_NUM + 1];
    pref[0] = 0;
    int off = 0;
#pragma unroll
    for (int e = 0; e < E_NUM; ++e) {
        ne_[e] = cnt[e];
        offs_[e] = off; off += ne_[e];
        pref[e + 1] = pref[e] + ((ne_[e] + 127) >> 7) * 16;   // nbm * 16 n-tiles
    }
    int T = pref[E_NUM];

    for (int w = blockIdx.x; w < T; w += gridDim.x) {
        int e = 0;
#pragma unroll
        for (int q = 0; q < E_NUM - 1; ++q) e += (w >= pref[q + 1]) ? 1 : 0;
        int local = w - pref[e];
        int bm0 = (local >> 4) * 128;
        int n0 = (local & 15) * 64;
        int ne = ne_[e];
        int offs = offs_[e];
        const unsigned short* w2e = w2t + (size_t)e * H_DIM * D_DIM;  // [n][k]

        __syncthreads();     // prev item done (epilogue reads s_tok/s_cf)
        if (tid < 128) {
            int gi = min(bm0 + tid, ne - 1);
            s_tok[tid] = tok[e * CAP + gi];
            s_cf[tid] = cf[e * CAP + gi];
        }
        __syncthreads();     // publish

        const unsigned short* gA[4];
        const unsigned short* gB[2];
#pragma unroll
        for (int l = 0; l < 4; ++l)
            gA[l] = Hbuf + (size_t)(offs + min(bm0 + wv * 32 + l * 8 + srow, ne - 1)) * H_DIM + schunk;
#pragma unroll
        for (int l = 0; l < 2; ++l)
            gB[l] = w2e + (size_t)(n0 + wv * 16 + l * 8 + srow) * H_DIM + schunk;

        float bias_v[2];
#pragma unroll
        for (int j = 0; j < 2; ++j) bias_v[j] = b2[(size_t)e * D_DIM + n0 + wc + j * 16 + lm];

        f32x4 acc[4][2];
#pragma unroll
        for (int i = 0; i < 4; ++i)
#pragma unroll
            for (int j = 0; j < 2; ++j) { f32x4 z = {0.f, 0.f, 0.f, 0.f}; acc[i][j] = z; }

        auto STAGE = [&](unsigned short (&A)[128][64], unsigned short (&B)[64][64], int kb) {
            int k0 = kb * 64;
#pragma unroll
            for (int l = 0; l < 4; ++l) gld_lds16(gA[l] + k0, &A[wv * 32 + l * 8][0]);
#pragma unroll
            for (int l = 0; l < 2; ++l) gld_lds16(gB[l] + k0, &B[wv * 16 + l * 8][0]);
        };
        auto COMPUTE = [&](unsigned short (&A)[128][64], unsigned short (&B)[64][64]) {
#pragma unroll
            for (int ks = 0; ks < 2; ++ks) {
                bf16x8 a[4], b[2];
                int c = (((ks * 4 + lk) ^ (lm & 7)) << 3);
#pragma unroll
                for (int f = 0; f < 4; ++f) a[f] = *(const bf16x8*)&A[wr + f * 16 + lm][c];
#pragma unroll
                for (int f = 0; f < 2; ++f) b[f] = *(const bf16x8*)&B[wc + f * 16 + lm][c];
                __builtin_amdgcn_s_setprio(1);
#pragma unroll
                for (int i = 0; i < 4; ++i)
#pragma unroll
                    for (int j = 0; j < 2; ++j)
                        acc[i][j] = __builtin_amdgcn_mfma_f32_16x16x32_bf16(a[i], b[j], acc[i][j], 0, 0, 0);
                __builtin_amdgcn_s_setprio(0);
            }
        };

        const int NT = H_DIM / 64;   // 64
        STAGE(As0, Bs0, 0);
        WAITV0; SBAR;
        for (int t = 0; t < NT; t += 2) {
            if (t + 1 < NT) STAGE(As1, Bs1, t + 1);
            COMPUTE(As0, Bs0);
            WAITV0; SBAR;
            if (t + 2 < NT) STAGE(As0, Bs0, t + 2);
            COMPUTE(As1, Bs1);
            WAITV0; SBAR;
        }

#pragma unroll
        for (int i = 0; i < 4; ++i) {
#pragma unroll
            for (int r = 0; r < 4; ++r) {
                int row = wr + i * 16 + lk * 4 + r;
                int gr = bm0 + row;
                if (gr >= ne) continue;
                int tk = s_tok[row];
                float cw = s_cf[row];
#pragma unroll
                for (int j = 0; j < 2; ++j) {
                    int gn = n0 + wc + j * 16 + lm;
                    float y = acc[i][j][r] + bias_v[j];
                    atomicAdd(&out[(size_t)tk * D_DIM + gn], cw * y);
                }
            }
        }
    }
}

extern "C" void kernel_launch(void* const* d_in, const int* in_sizes, int n_in,
                              void* d_out, int out_size, void* d_ws, size_t ws_size,
                              hipStream_t stream) {
    const float* x  = (const float*)d_in[0];
    const float* gw = (const float*)d_in[1];
    const float* w1 = (const float*)d_in[2];
    const float* b1 = (const float*)d_in[3];
    const float* w2 = (const float*)d_in[4];
    const float* b2 = (const float*)d_in[5];
    float* out = (float*)d_out;

    char* ws = (char*)d_ws;
    const size_t SZ_ROUTE = 256 + (size_t)2 * E_NUM * CAP * 4;
    const size_t SZ_XB    = (size_t)T_TOKENS * D_DIM * 2;
    const size_t SZ_W     = (size_t)E_NUM * D_DIM * H_DIM * 2;
    const size_t SZ_H     = (size_t)2 * T_TOKENS * H_DIM * 2;

    int*   cnt = (int*)ws;
    int*   tok = (int*)(ws + 256);
    float* cff = (float*)(ws + 256 + E_NUM * CAP * 4);

    size_t need_fast = SZ_ROUTE + SZ_XB + 2 * SZ_W + SZ_H;
    if (ws_size < need_fast) return;  // loud failure: out stays poisoned

    unsigned short* xb   = (unsigned short*)(ws + SZ_ROUTE);
    unsigned short* w1t  = (unsigned short*)(ws + SZ_ROUTE + SZ_XB);
    unsigned short* w2t  = (unsigned short*)(ws + SZ_ROUTE + SZ_XB + SZ_W);
    unsigned short* Hbuf = (unsigned short*)(ws + SZ_ROUTE + SZ_XB + 2 * SZ_W);

    hipMemsetAsync(cnt, 0, E_NUM * sizeof(int), stream);
    hipMemsetAsync(out, 0, (size_t)out_size * sizeof(float), stream);

    gate_kernel<<<T_TOKENS / 4, 256, 0, stream>>>(x, gw, cnt, tok, cff, xb);

    dim3 gt1(H_DIM / 128, D_DIM / 64, E_NUM);
    trw_kernel<<<gt1, 256, 0, stream>>>(w1, w1t, D_DIM, H_DIM);
    dim3 gt2(D_DIM / 128, H_DIM / 64, E_NUM);
    trw_kernel<<<gt2, 256, 0, stream>>>(w2, w2t, H_DIM, D_DIM);

    gemm1_fast<<<512, 256, 0, stream>>>(xb, w1t, b1, cnt, tok, Hbuf);
    gemm2_fast<<<768, 256, 0, stream>>>(Hbuf, w2t, b2, cnt, tok, cff, out);
}